// Round 1
// baseline (2840.522 us; speedup 1.0000x reference)
//
#include <hip/hip_runtime.h>
#include <hip/hip_bf16.h>
#include <math.h>

#define T_DIM 2048
#define E_DIM 1536
#define H_DIM 16
#define KVH_DIM 8
#define M_DIM 3
#define HD_DIM 32

// ---------------- GEMM: C[M,N] = A[M,K] * B[N,K]^T (both row-major, dot over K)
#define BM 64
#define BN 64
#define BK 16

__global__ __launch_bounds__(256) void gemm_bt(const float* __restrict__ A,
                                               const float* __restrict__ B,
                                               float* __restrict__ C,
                                               int Mr, int Nr, int Kr) {
    __shared__ float As[BK][BM + 4];
    __shared__ float Bs[BK][BN + 4];
    const int tid = threadIdx.x;
    const int tx = tid & 15;   // n direction
    const int ty = tid >> 4;   // m direction
    const int bm = blockIdx.y * BM;
    const int bn = blockIdx.x * BN;

    const int lr = tid >> 2;        // 0..63: tile row
    const int lc = (tid & 3) * 4;   // 0,4,8,12: k offset

    float acc[4][4];
#pragma unroll
    for (int i = 0; i < 4; ++i)
#pragma unroll
        for (int j = 0; j < 4; ++j) acc[i][j] = 0.f;

    for (int k0 = 0; k0 < Kr; k0 += BK) {
        float4 av = *(const float4*)(A + (size_t)(bm + lr) * Kr + k0 + lc);
        float4 bv = *(const float4*)(B + (size_t)(bn + lr) * Kr + k0 + lc);
        As[lc + 0][lr] = av.x; As[lc + 1][lr] = av.y;
        As[lc + 2][lr] = av.z; As[lc + 3][lr] = av.w;
        Bs[lc + 0][lr] = bv.x; Bs[lc + 1][lr] = bv.y;
        Bs[lc + 2][lr] = bv.z; Bs[lc + 3][lr] = bv.w;
        __syncthreads();
#pragma unroll
        for (int kk = 0; kk < BK; ++kk) {
            float4 a4 = *(const float4*)&As[kk][ty * 4];
            float4 b4 = *(const float4*)&Bs[kk][tx * 4];
            float a[4] = {a4.x, a4.y, a4.z, a4.w};
            float b[4] = {b4.x, b4.y, b4.z, b4.w};
#pragma unroll
            for (int i = 0; i < 4; ++i)
#pragma unroll
                for (int j = 0; j < 4; ++j) acc[i][j] += a[i] * b[j];
        }
        __syncthreads();
    }

#pragma unroll
    for (int i = 0; i < 4; ++i) {
        float4 o = make_float4(acc[i][0], acc[i][1], acc[i][2], acc[i][3]);
        *(float4*)(C + (size_t)(bm + ty * 4 + i) * Nr + bn + tx * 4) = o;
    }
}

// ---------------- RoPE (interleaved) in-place; optional scaling (for Q)
__global__ __launch_bounds__(256) void rope_kernel(float* __restrict__ buf,
                                                   const float* __restrict__ cosb,
                                                   const float* __restrict__ sinb,
                                                   int nh, int rowstride, float scale,
                                                   int total) {
    int p = blockIdx.x * blockDim.x + threadIdx.x;
    if (p >= total) return;
    int i = p & 15;
    int hh = (p >> 4) % nh;
    int m = ((p >> 4) / nh) % M_DIM;
    int t = p / (16 * nh * M_DIM);
    float c = cosb[t * 16 + i];
    float s = sinb[t * 16 + i];
    float* ptr = buf + (size_t)t * rowstride + m * (nh * HD_DIM) + hh * HD_DIM + 2 * i;
    float x1 = ptr[0], x2 = ptr[1];
    ptr[0] = (x1 * c - x2 * s) * scale;
    ptr[1] = (x1 * s + x2 * c) * scale;
}

// ---------------- Attention: flash-style, 3 ensembles per wave, fused combine+RMS
// grid: (T/4, H). block: 256 (4 waves). wave handles one query row t for head h.
// q layout: (T, 1536) col = m*512 + h*32 + d   (already RoPE'd + scaled)
// k layout: (T, 768)  col = m*256 + kv*32 + d  (already RoPE'd)
// v layout: (T, 768)  col = kv*96 + f
// out layout: (T, 1536) col = h*96 + f
__global__ __launch_bounds__(256) void attn_kernel(const float* __restrict__ q,
                                                   const float* __restrict__ k,
                                                   const float* __restrict__ v,
                                                   const float* __restrict__ raw_map,
                                                   const float* __restrict__ wscale,
                                                   const float* __restrict__ subln,
                                                   float* __restrict__ outb) {
    const int wave = threadIdx.x >> 6;
    const int lane = threadIdx.x & 63;
    const int t = blockIdx.x * 4 + wave;
    const int h = blockIdx.y;
    const int kv = h >> 1;

    // Q row into registers: 3 x 32 floats
    float qr[3][32];
#pragma unroll
    for (int m = 0; m < M_DIM; ++m) {
        const float4* qp = (const float4*)(q + (size_t)t * E_DIM + m * 512 + h * HD_DIM);
#pragma unroll
        for (int u = 0; u < 8; ++u) {
            float4 val = qp[u];
            qr[m][u * 4 + 0] = val.x; qr[m][u * 4 + 1] = val.y;
            qr[m][u * 4 + 2] = val.z; qr[m][u * 4 + 3] = val.w;
        }
    }

    float o0[3] = {0.f, 0.f, 0.f};
    float o1[3] = {0.f, 0.f, 0.f};
    float rm[3] = {-1e30f, -1e30f, -1e30f};
    float rl[3] = {0.f, 0.f, 0.f};
    const int f0 = lane;
    const int f1s = 64 + (lane & 31);

    for (int s0 = 0; s0 <= t; s0 += 64) {
        const int s = s0 + lane;
        const bool valid = (s <= t);
        float p[3];
        const float* krow = k + (size_t)s * 768 + kv * HD_DIM;
#pragma unroll
        for (int m = 0; m < M_DIM; ++m) {
            float acc = 0.f;
            const float4* kp = (const float4*)(krow + m * 256);
#pragma unroll
            for (int u = 0; u < 8; ++u) {
                float4 kv4 = kp[u];
                acc += qr[m][u * 4 + 0] * kv4.x;
                acc += qr[m][u * 4 + 1] * kv4.y;
                acc += qr[m][u * 4 + 2] * kv4.z;
                acc += qr[m][u * 4 + 3] * kv4.w;
            }
            p[m] = valid ? acc : -1e30f;
        }
#pragma unroll
        for (int m = 0; m < M_DIM; ++m) {
            float cm = p[m];
            for (int off = 32; off > 0; off >>= 1)
                cm = fmaxf(cm, __shfl_xor(cm, off, 64));
            float nm = fmaxf(rm[m], cm);
            float sc = expf(rm[m] - nm);
            p[m] = expf(p[m] - nm);
            float ps = p[m];
            for (int off = 32; off > 0; off >>= 1)
                ps += __shfl_xor(ps, off, 64);
            rl[m] = rl[m] * sc + ps;
            rm[m] = nm;
            o0[m] *= sc; o1[m] *= sc;
        }
        // PV accumulate over the 64 keys of this chunk
        const float* vrow = v + (size_t)s0 * 768 + kv * 96;
        for (int j = 0; j < 64; ++j) {
            float v0 = vrow[(size_t)j * 768 + f0];
            float v1 = vrow[(size_t)j * 768 + f1s];
            float p0 = __shfl(p[0], j, 64);
            float p1 = __shfl(p[1], j, 64);
            float p2 = __shfl(p[2], j, 64);
            o0[0] += p0 * v0; o1[0] += p0 * v1;
            o0[1] += p1 * v0; o1[1] += p1 * v1;
            o0[2] += p2 * v0; o1[2] += p2 * v1;
        }
    }

    // ensemble combine
    float wsc = wscale[0];
    float mw0 = tanhf(raw_map[0]) * wsc;
    float mw1 = tanhf(raw_map[1]) * wsc;
    float mw2 = tanhf(raw_map[2]) * wsc;
    float a0 = mw0 * o0[0] / rl[0] + mw1 * o0[1] / rl[1] + mw2 * o0[2] / rl[2];
    float a1 = mw0 * o1[0] / rl[0] + mw1 * o1[1] / rl[1] + mw2 * o1[2] / rl[2];

    // RMS over the 96 features of this (h, t)
    float ss = a0 * a0 + ((lane < 32) ? a1 * a1 : 0.f);
    for (int off = 32; off > 0; off >>= 1)
        ss += __shfl_xor(ss, off, 64);
    float r = rsqrtf(ss / 96.f + 1e-5f);

    float* orow = outb + (size_t)t * E_DIM + h * 96;
    orow[f0] = a0 * r * subln[f0];
    if (lane < 32) orow[f1s] = a1 * r * subln[f1s];
}

extern "C" void kernel_launch(void* const* d_in, const int* in_sizes, int n_in,
                              void* d_out, int out_size, void* d_ws, size_t ws_size,
                              hipStream_t stream) {
    const float* x       = (const float*)d_in[0];  // (T, E)
    const float* cosb    = (const float*)d_in[1];  // (T, 16)
    const float* sinb    = (const float*)d_in[2];  // (T, 16)
    const float* q_w     = (const float*)d_in[3];  // (3, 512, 1536)
    const float* k_w     = (const float*)d_in[4];  // (3, 256, 1536)
    const float* v_w     = (const float*)d_in[5];  // (768, 1536)
    const float* out_w   = (const float*)d_in[6];  // (1536, 1536)
    const float* raw_map = (const float*)d_in[7];  // (3,)
    const float* wscale  = (const float*)d_in[8];  // (1,)
    const float* subln   = (const float*)d_in[9];  // (96,)
    float* out = (float*)d_out;

    float* ws = (float*)d_ws;
    float* qbuf = ws;                                  // T*1536
    float* kbuf = qbuf + (size_t)T_DIM * E_DIM;        // T*768
    float* vbuf = kbuf + (size_t)T_DIM * 768;          // T*768
    float* abuf = vbuf + (size_t)T_DIM * 768;          // T*1536

    // Projections (C = A * W^T)
    gemm_bt<<<dim3(E_DIM / BN, T_DIM / BM), 256, 0, stream>>>(x, q_w, qbuf, T_DIM, E_DIM, E_DIM);
    gemm_bt<<<dim3(768 / BN, T_DIM / BM), 256, 0, stream>>>(x, k_w, kbuf, T_DIM, 768, E_DIM);
    gemm_bt<<<dim3(768 / BN, T_DIM / BM), 256, 0, stream>>>(x, v_w, vbuf, T_DIM, 768, E_DIM);

    // RoPE (q gets scaling = hd^-0.5 fused)
    const float scaling = 0.17677669529663687f; // 32^-0.5
    int totq = T_DIM * M_DIM * H_DIM * 16;
    int totk = T_DIM * M_DIM * KVH_DIM * 16;
    rope_kernel<<<(totq + 255) / 256, 256, 0, stream>>>(qbuf, cosb, sinb, H_DIM, E_DIM, scaling, totq);
    rope_kernel<<<(totk + 255) / 256, 256, 0, stream>>>(kbuf, cosb, sinb, KVH_DIM, 768, 1.f, totk);

    // Attention + ensemble combine + RMS/subln
    attn_kernel<<<dim3(T_DIM / 4, H_DIM), 256, 0, stream>>>(qbuf, kbuf, vbuf, raw_map, wscale, subln, abuf);

    // Output projection
    gemm_bt<<<dim3(E_DIM / BN, T_DIM / BM), 256, 0, stream>>>(abuf, out_w, out, T_DIM, E_DIM, E_DIM);
}

// Round 2
// 662.238 us; speedup vs baseline: 4.2893x; 4.2893x over previous
//
#include <hip/hip_runtime.h>
#include <math.h>

#define T_DIM 2048
#define E_DIM 1536

typedef unsigned short u16;
typedef __attribute__((ext_vector_type(8))) short bf16x8;
typedef __attribute__((ext_vector_type(4))) float f32x4;

__device__ __forceinline__ u16 f2bf(float x) {
    unsigned u = __float_as_uint(x);
    return (u16)((u + 0x7fffu + ((u >> 16) & 1u)) >> 16);
}

// ---------------- GEMM: C[M,N] = A[M,K] * B[N,K]^T (fp32, unchanged)
#define BM 64
#define BN 64
#define BK 16

__global__ __launch_bounds__(256) void gemm_bt(const float* __restrict__ A,
                                               const float* __restrict__ B,
                                               float* __restrict__ C,
                                               int Mr, int Nr, int Kr) {
    __shared__ float As[BK][BM + 4];
    __shared__ float Bs[BK][BN + 4];
    const int tid = threadIdx.x;
    const int tx = tid & 15;
    const int ty = tid >> 4;
    const int bm = blockIdx.y * BM;
    const int bn = blockIdx.x * BN;

    const int lr = tid >> 2;
    const int lc = (tid & 3) * 4;

    float acc[4][4];
#pragma unroll
    for (int i = 0; i < 4; ++i)
#pragma unroll
        for (int j = 0; j < 4; ++j) acc[i][j] = 0.f;

    for (int k0 = 0; k0 < Kr; k0 += BK) {
        float4 av = *(const float4*)(A + (size_t)(bm + lr) * Kr + k0 + lc);
        float4 bv = *(const float4*)(B + (size_t)(bn + lr) * Kr + k0 + lc);
        As[lc + 0][lr] = av.x; As[lc + 1][lr] = av.y;
        As[lc + 2][lr] = av.z; As[lc + 3][lr] = av.w;
        Bs[lc + 0][lr] = bv.x; Bs[lc + 1][lr] = bv.y;
        Bs[lc + 2][lr] = bv.z; Bs[lc + 3][lr] = bv.w;
        __syncthreads();
#pragma unroll
        for (int kk = 0; kk < BK; ++kk) {
            float4 a4 = *(const float4*)&As[kk][ty * 4];
            float4 b4 = *(const float4*)&Bs[kk][tx * 4];
            float a[4] = {a4.x, a4.y, a4.z, a4.w};
            float b[4] = {b4.x, b4.y, b4.z, b4.w};
#pragma unroll
            for (int i = 0; i < 4; ++i)
#pragma unroll
                for (int j = 0; j < 4; ++j) acc[i][j] += a[i] * b[j];
        }
        __syncthreads();
    }

#pragma unroll
    for (int i = 0; i < 4; ++i) {
        float4 o = make_float4(acc[i][0], acc[i][1], acc[i][2], acc[i][3]);
        *(float4*)(C + (size_t)(bm + ty * 4 + i) * Nr + bn + tx * 4) = o;
    }
}

// ---------------- RoPE + scale + fp32->bf16 convert (same layout)
__global__ __launch_bounds__(256) void rope_cvt(const float* __restrict__ in,
                                                u16* __restrict__ outb,
                                                const float* __restrict__ cosb,
                                                const float* __restrict__ sinb,
                                                int nh, int rowlen, float scale, int total) {
    int p = blockIdx.x * 256 + threadIdx.x;
    if (p >= total) return;
    int i = p & 15;
    int hh = (p >> 4) % nh;
    int m = ((p >> 4) / nh) % 3;
    int t = p / (16 * nh * 3);
    float c = cosb[t * 16 + i];
    float s = sinb[t * 16 + i];
    size_t off = (size_t)t * rowlen + m * (nh * 32) + hh * 32 + 2 * i;
    float x1 = in[off], x2 = in[off + 1];
    float o1 = (x1 * c - x2 * s) * scale;
    float o2 = (x1 * s + x2 * c) * scale;
    *(ushort2*)(outb + off) = make_ushort2(f2bf(o1), f2bf(o2));
}

// ---------------- V: [T][768] fp32 -> [768][T] bf16 (transposed)
__global__ __launch_bounds__(256) void v_cvt_t(const float* __restrict__ v, u16* __restrict__ vt) {
    int id = blockIdx.x * 256 + threadIdx.x;
    int t = id & (T_DIM - 1);
    int rowi = id >> 11;
    vt[(size_t)rowi * T_DIM + t] = f2bf(v[(size_t)t * 768 + rowi]);
}

// ---------------- MFMA flash attention, 3 ensembles, fused combine+RMS+subln
// 1 wave per block; wave handles 16 q rows of head h, all 3 ensembles.
// qb: (T,1536) bf16, col = m*512 + h*32 + d   (rope'd, pre-scaled by hd^-0.5 * log2e)
// kb: (T,768)  bf16, col = m*256 + kv*32 + d  (rope'd)
// vt: (768,T)  bf16, row = kv*96 + f
// outb: (T,1536) fp32, col = h*96 + f
__global__ __launch_bounds__(64) void attn_mfma(const u16* __restrict__ qb,
                                                const u16* __restrict__ kb,
                                                const u16* __restrict__ vt,
                                                const float* __restrict__ raw_map,
                                                const float* __restrict__ wscale,
                                                const float* __restrict__ subln,
                                                float* __restrict__ outb) {
    __shared__ u16 plds[3][16][40];   // [ens][qrow][key(32) + pad]; wave-private, no barriers
    const int lane = threadIdx.x;
    const int col = lane & 15;
    const int g = lane >> 4;
    const int qbase = (127 - blockIdx.x) * 16;   // heaviest tiles first
    const int h = blockIdx.y;
    const int kvh = h >> 1;
    const int t_hi = qbase + 15;

    // Q B-fragments: lane holds q-row (col), d = 8g..8g+7
    bf16x8 qfrag[3];
#pragma unroll
    for (int m = 0; m < 3; ++m)
        qfrag[m] = *(const bf16x8*)(qb + (size_t)(qbase + col) * E_DIM + m * 512 + h * 32 + 8 * g);

    f32x4 oacc[3][6];
#pragma unroll
    for (int m = 0; m < 3; ++m)
#pragma unroll
        for (int ft = 0; ft < 6; ++ft) oacc[m][ft] = (f32x4){0.f, 0.f, 0.f, 0.f};
    float lsum[3] = {0.f, 0.f, 0.f};

    for (int s0 = 0; s0 <= t_hi; s0 += 32) {
        const bool need_mask = (s0 + 31 > qbase);
        // ---- S^T = K_tile * Q^T : D[key][qrow], col=qrow, row=key_local
#pragma unroll
        for (int m = 0; m < 3; ++m) {
            const u16* kbase = kb + m * 256 + kvh * 32 + 8 * g;
#pragma unroll
            for (int st = 0; st < 2; ++st) {
                bf16x8 kf = *(const bf16x8*)(kbase + (size_t)(s0 + st * 16 + col) * 768);
                f32x4 sv = __builtin_amdgcn_mfma_f32_16x16x32_bf16(
                    kf, qfrag[m], (f32x4){0.f, 0.f, 0.f, 0.f}, 0, 0, 0);
                float p[4];
#pragma unroll
                for (int r = 0; r < 4; ++r) {
                    float x = sv[r];
                    if (need_mask && (s0 + st * 16 + 4 * g + r > qbase + col)) x = -1e30f;
                    p[r] = __builtin_amdgcn_exp2f(x);   // no max-subtract: |scores| small by construction
                    lsum[m] += p[r];
                }
                *(ushort2*)&plds[m][col][st * 16 + 4 * g]     = make_ushort2(f2bf(p[0]), f2bf(p[1]));
                *(ushort2*)&plds[m][col][st * 16 + 4 * g + 2] = make_ushort2(f2bf(p[2]), f2bf(p[3]));
            }
        }
        asm volatile("s_waitcnt lgkmcnt(0)" ::: "memory");
        // ---- P A-fragments from LDS: lane holds qrow=col, keys 8g..8g+7
        bf16x8 pf[3];
#pragma unroll
        for (int m = 0; m < 3; ++m)
            pf[m] = *(const bf16x8*)&plds[m][col][8 * g];
        // ---- PV: D[qrow][f], B = V^T rows (f), 8 contiguous keys per lane
        const u16* vbase = vt + (size_t)(kvh * 96) * T_DIM + s0 + 8 * g;
#pragma unroll
        for (int ft = 0; ft < 6; ++ft) {
            bf16x8 vf = *(const bf16x8*)(vbase + (size_t)(ft * 16 + col) * T_DIM);
#pragma unroll
            for (int m = 0; m < 3; ++m)
                oacc[m][ft] = __builtin_amdgcn_mfma_f32_16x16x32_bf16(pf[m], vf, oacc[m][ft], 0, 0, 0);
        }
        asm volatile("" ::: "memory");   // keep next iter's LDS writes behind this iter's reads
    }

    // ---- epilogue: finish row sums, combine ensembles, RMS + subln, store fp32
#pragma unroll
    for (int m = 0; m < 3; ++m) {
        lsum[m] += __shfl_xor(lsum[m], 16, 64);
        lsum[m] += __shfl_xor(lsum[m], 32, 64);   // now lane holds full sum for qrow=col
    }
    float wsc = wscale[0];
    float mw[3];
#pragma unroll
    for (int m = 0; m < 3; ++m) mw[m] = tanhf(raw_map[m]) * wsc;

    // PV output layout: col = f, row(qrow) = 4g+r -> fetch that row's lsum via shfl
    float fac[3][4];
#pragma unroll
    for (int m = 0; m < 3; ++m)
#pragma unroll
        for (int r = 0; r < 4; ++r)
            fac[m][r] = mw[m] / __shfl(lsum[m], 4 * g + r, 64);

    float av[6][4];
    float ss[4] = {0.f, 0.f, 0.f, 0.f};
#pragma unroll
    for (int ft = 0; ft < 6; ++ft)
#pragma unroll
        for (int r = 0; r < 4; ++r) {
            float v = fac[0][r] * oacc[0][ft][r] + fac[1][r] * oacc[1][ft][r] + fac[2][r] * oacc[2][ft][r];
            av[ft][r] = v;
            ss[r] += v * v;
        }
#pragma unroll
    for (int r = 0; r < 4; ++r) {
        ss[r] += __shfl_xor(ss[r], 1, 64);
        ss[r] += __shfl_xor(ss[r], 2, 64);
        ss[r] += __shfl_xor(ss[r], 4, 64);
        ss[r] += __shfl_xor(ss[r], 8, 64);
        ss[r] = rsqrtf(ss[r] * (1.f / 96.f) + 1e-5f);
    }
#pragma unroll
    for (int ft = 0; ft < 6; ++ft) {
        float sl = subln[ft * 16 + col];
#pragma unroll
        for (int r = 0; r < 4; ++r) {
            int trow = qbase + 4 * g + r;
            outb[(size_t)trow * E_DIM + h * 96 + ft * 16 + col] = av[ft][r] * ss[r] * sl;
        }
    }
}

extern "C" void kernel_launch(void* const* d_in, const int* in_sizes, int n_in,
                              void* d_out, int out_size, void* d_ws, size_t ws_size,
                              hipStream_t stream) {
    const float* x       = (const float*)d_in[0];
    const float* cosb    = (const float*)d_in[1];
    const float* sinb    = (const float*)d_in[2];
    const float* q_w     = (const float*)d_in[3];
    const float* k_w     = (const float*)d_in[4];
    const float* v_w     = (const float*)d_in[5];
    const float* out_w   = (const float*)d_in[6];
    const float* raw_map = (const float*)d_in[7];
    const float* wscale  = (const float*)d_in[8];
    const float* subln   = (const float*)d_in[9];
    float* out = (float*)d_out;

    float* qbuf = (float*)d_ws;                        // T*1536 f32 (reused as abuf)
    float* kbuf = qbuf + (size_t)T_DIM * E_DIM;        // T*768 f32
    float* vbuf = kbuf + (size_t)T_DIM * 768;          // T*768 f32
    u16* qb16 = (u16*)(vbuf + (size_t)T_DIM * 768);    // T*1536 bf16
    u16* kb16 = qb16 + (size_t)T_DIM * E_DIM;          // T*768 bf16
    u16* vt16 = kb16 + (size_t)T_DIM * 768;            // 768*T bf16 (transposed)
    float* abuf = qbuf;                                // alias: qbuf dead after rope_cvt

    // Projections (fp32)
    gemm_bt<<<dim3(E_DIM / BN, T_DIM / BM), 256, 0, stream>>>(x, q_w, qbuf, T_DIM, E_DIM, E_DIM);
    gemm_bt<<<dim3(768 / BN, T_DIM / BM), 256, 0, stream>>>(x, k_w, kbuf, T_DIM, 768, E_DIM);
    gemm_bt<<<dim3(768 / BN, T_DIM / BM), 256, 0, stream>>>(x, v_w, vbuf, T_DIM, 768, E_DIM);

    // RoPE + convert. Q gets hd^-0.5 * log2(e) folded in (softmax uses exp2).
    const float qscale = 0.17677669529663687f * 1.4426950408889634f;
    int totq = T_DIM * 3 * 16 * 16;
    int totk = T_DIM * 3 * 8 * 16;
    rope_cvt<<<(totq + 255) / 256, 256, 0, stream>>>(qbuf, qb16, cosb, sinb, 16, E_DIM, qscale, totq);
    rope_cvt<<<(totk + 255) / 256, 256, 0, stream>>>(kbuf, kb16, cosb, sinb, 8, 768, 1.f, totk);
    v_cvt_t<<<(768 * T_DIM) / 256, 256, 0, stream>>>(vbuf, vt16);

    // Attention (MFMA) + combine + RMS + subln -> abuf fp32
    attn_mfma<<<dim3(T_DIM / 16, 16), 64, 0, stream>>>(qb16, kb16, vt16, raw_map, wscale, subln, abuf);

    // Output projection (fp32)
    gemm_bt<<<dim3(E_DIM / BN, T_DIM / BM), 256, 0, stream>>>(abuf, out_w, out, T_DIM, E_DIM, E_DIM);
}

// Round 3
// 260.154 us; speedup vs baseline: 10.9186x; 2.5456x over previous
//
#include <hip/hip_runtime.h>
#include <math.h>

#define T_DIM 2048
#define E_DIM 1536
#define K_DIM 1536

typedef unsigned short u16;
typedef unsigned int u32;
typedef __attribute__((ext_vector_type(8))) short bf16x8;
typedef __attribute__((ext_vector_type(4))) float f32x4;

__device__ __forceinline__ u16 f2bf(float x) {
    unsigned u = __float_as_uint(x);
    return (u16)((u + 0x7fffu + ((u >> 16) & 1u)) >> 16);
}
__device__ __forceinline__ float bf2f(u16 x) {
    unsigned u = ((unsigned)x) << 16;
    return __uint_as_float(u);
}

#define GLOAD16(gsrc, ldst)                                                              \
    __builtin_amdgcn_global_load_lds((const __attribute__((address_space(1))) u32*)(gsrc), \
                                     (__attribute__((address_space(3))) u32*)(ldst), 16, 0, 0)

// ---------------- f32 -> bf16 elementwise (4 per thread)
__global__ __launch_bounds__(256) void cvt_bf16(const float* __restrict__ in,
                                                u16* __restrict__ out, int n4) {
    int i = blockIdx.x * 256 + threadIdx.x;
    if (i >= n4) return;
    float4 v = ((const float4*)in)[i];
    ushort4 o = make_ushort4(f2bf(v.x), f2bf(v.y), f2bf(v.z), f2bf(v.w));
    ((ushort4*)out)[i] = o;
}

// ---------------- bf16 MFMA GEMM: C[M,N] = A[M,K] * W[N,K]^T
// tile 128x64, BK=64, 4 waves (2x2), wave tile 64x32.
// LDS rows are 128B; XOR-swizzle byte^((row&7)<<4) applied on BOTH the staged
// global source and the ds_read address (involution) -> conflict-free b128 reads.
template <int OUT_BF16>
__global__ __launch_bounds__(256) void gemm_mfma(const u16* __restrict__ A,
                                                 const u16* __restrict__ W,
                                                 void* __restrict__ Cp,
                                                 int K, int ldC) {
    __shared__ __align__(16) u16 As[128 * 64];
    __shared__ __align__(16) u16 Bs[64 * 64];
    const int tid = threadIdx.x;
    const int lane = tid & 63;
    const int wv = tid >> 6;
    const int wr = wv >> 1;
    const int wc = wv & 1;
    const int cl = lane & 15;
    const int g = lane >> 4;
    const int bm = blockIdx.y * 128;
    const int bn = blockIdx.x * 64;

    const char* Ab = (const char*)A;
    const char* Wb = (const char*)W;

    // staging maps (byte b in tile -> row, swizzled source offset)
    size_t a_src[4];
    int a_dst[4];
#pragma unroll
    for (int is = 0; is < 4; ++is) {
        int b = is * 4096 + wv * 1024 + lane * 16;
        int row = b >> 7;
        int wi = b & 127;
        a_src[is] = (size_t)(bm + row) * (K * 2) + (wi ^ ((row & 7) << 4));
        a_dst[is] = b;
    }
    size_t b_src[2];
    int b_dst[2];
#pragma unroll
    for (int is = 0; is < 2; ++is) {
        int b = is * 4096 + wv * 1024 + lane * 16;
        int row = b >> 7;
        int wi = b & 127;
        b_src[is] = (size_t)(bn + row) * (K * 2) + (wi ^ ((row & 7) << 4));
        b_dst[is] = b;
    }

    f32x4 acc[4][2];
#pragma unroll
    for (int mi = 0; mi < 4; ++mi)
#pragma unroll
        for (int ni = 0; ni < 2; ++ni) acc[mi][ni] = (f32x4){0.f, 0.f, 0.f, 0.f};

    for (int k0b = 0; k0b < K * 2; k0b += 128) {
#pragma unroll
        for (int is = 0; is < 4; ++is)
            GLOAD16(Ab + a_src[is] + k0b, (char*)As + a_dst[is]);
#pragma unroll
        for (int is = 0; is < 2; ++is)
            GLOAD16(Wb + b_src[is] + k0b, (char*)Bs + b_dst[is]);
        __syncthreads();
#pragma unroll
        for (int kk = 0; kk < 2; ++kk) {
            const int co = (kk * 64 + g * 16) ^ ((cl & 7) << 4);
            bf16x8 af[4], bfr[2];
#pragma unroll
            for (int mi = 0; mi < 4; ++mi)
                af[mi] = *(const bf16x8*)((const char*)As + (wr * 64 + mi * 16 + cl) * 128 + co);
#pragma unroll
            for (int ni = 0; ni < 2; ++ni)
                bfr[ni] = *(const bf16x8*)((const char*)Bs + (wc * 32 + ni * 16 + cl) * 128 + co);
#pragma unroll
            for (int mi = 0; mi < 4; ++mi)
#pragma unroll
                for (int ni = 0; ni < 2; ++ni)
                    acc[mi][ni] = __builtin_amdgcn_mfma_f32_16x16x32_bf16(af[mi], bfr[ni], acc[mi][ni], 0, 0, 0);
        }
        __syncthreads();
    }

#pragma unroll
    for (int mi = 0; mi < 4; ++mi)
#pragma unroll
        for (int ni = 0; ni < 2; ++ni)
#pragma unroll
            for (int r = 0; r < 4; ++r) {
                size_t row = bm + wr * 64 + mi * 16 + 4 * g + r;
                size_t col = bn + wc * 32 + ni * 16 + cl;
                if (OUT_BF16)
                    ((u16*)Cp)[row * ldC + col] = f2bf(acc[mi][ni][r]);
                else
                    ((float*)Cp)[row * ldC + col] = acc[mi][ni][r];
            }
}

// ---------------- RoPE (bf16 in/out) + optional scale
__global__ __launch_bounds__(256) void rope_cvt16(const u16* __restrict__ in,
                                                  u16* __restrict__ outb,
                                                  const float* __restrict__ cosb,
                                                  const float* __restrict__ sinb,
                                                  int nh, int inld, int incol0, int outld,
                                                  float scale, int total) {
    int p = blockIdx.x * 256 + threadIdx.x;
    if (p >= total) return;
    int i = p & 15;
    int hh = (p >> 4) % nh;
    int m = ((p >> 4) / nh) % 3;
    int t = p / (16 * nh * 3);
    float c = cosb[t * 16 + i];
    float s = sinb[t * 16 + i];
    size_t ioff = (size_t)t * inld + incol0 + m * (nh * 32) + hh * 32 + 2 * i;
    ushort2 xv = *(const ushort2*)(in + ioff);
    float x1 = bf2f(xv.x), x2 = bf2f(xv.y);
    float o1 = (x1 * c - x2 * s) * scale;
    float o2 = (x1 * s + x2 * c) * scale;
    size_t ooff = (size_t)t * outld + m * (nh * 32) + hh * 32 + 2 * i;
    *(ushort2*)(outb + ooff) = make_ushort2(f2bf(o1), f2bf(o2));
}

// ---------------- V slice transpose: qkv[t][2304+f] -> vt[f][t] (bf16 copy)
__global__ __launch_bounds__(256) void v_t16(const u16* __restrict__ in, u16* __restrict__ vt) {
    int id = blockIdx.x * 256 + threadIdx.x;
    int t = id & (T_DIM - 1);
    int f = id >> 11;
    vt[(size_t)f * T_DIM + t] = in[(size_t)t * 3072 + 2304 + f];
}

// ---------------- MFMA flash attention (unchanged structure; bf16 output)
__global__ __launch_bounds__(64) void attn_mfma(const u16* __restrict__ qb,
                                                const u16* __restrict__ kb,
                                                const u16* __restrict__ vt,
                                                const float* __restrict__ raw_map,
                                                const float* __restrict__ wscale,
                                                const float* __restrict__ subln,
                                                u16* __restrict__ outb) {
    __shared__ u16 plds[3][16][40];
    const int lane = threadIdx.x;
    const int col = lane & 15;
    const int g = lane >> 4;
    const int qbase = (127 - blockIdx.x) * 16;
    const int h = blockIdx.y;
    const int kvh = h >> 1;
    const int t_hi = qbase + 15;

    bf16x8 qfrag[3];
#pragma unroll
    for (int m = 0; m < 3; ++m)
        qfrag[m] = *(const bf16x8*)(qb + (size_t)(qbase + col) * E_DIM + m * 512 + h * 32 + 8 * g);

    f32x4 oacc[3][6];
#pragma unroll
    for (int m = 0; m < 3; ++m)
#pragma unroll
        for (int ft = 0; ft < 6; ++ft) oacc[m][ft] = (f32x4){0.f, 0.f, 0.f, 0.f};
    float lsum[3] = {0.f, 0.f, 0.f};

    for (int s0 = 0; s0 <= t_hi; s0 += 32) {
        const bool need_mask = (s0 + 31 > qbase);
#pragma unroll
        for (int m = 0; m < 3; ++m) {
            const u16* kbase = kb + m * 256 + kvh * 32 + 8 * g;
#pragma unroll
            for (int st = 0; st < 2; ++st) {
                bf16x8 kf = *(const bf16x8*)(kbase + (size_t)(s0 + st * 16 + col) * 768);
                f32x4 sv = __builtin_amdgcn_mfma_f32_16x16x32_bf16(
                    kf, qfrag[m], (f32x4){0.f, 0.f, 0.f, 0.f}, 0, 0, 0);
                float p[4];
#pragma unroll
                for (int r = 0; r < 4; ++r) {
                    float x = sv[r];
                    if (need_mask && (s0 + st * 16 + 4 * g + r > qbase + col)) x = -1e30f;
                    p[r] = __builtin_amdgcn_exp2f(x);
                    lsum[m] += p[r];
                }
                *(ushort2*)&plds[m][col][st * 16 + 4 * g]     = make_ushort2(f2bf(p[0]), f2bf(p[1]));
                *(ushort2*)&plds[m][col][st * 16 + 4 * g + 2] = make_ushort2(f2bf(p[2]), f2bf(p[3]));
            }
        }
        asm volatile("s_waitcnt lgkmcnt(0)" ::: "memory");
        bf16x8 pf[3];
#pragma unroll
        for (int m = 0; m < 3; ++m)
            pf[m] = *(const bf16x8*)&plds[m][col][8 * g];
        const u16* vbase = vt + (size_t)(kvh * 96) * T_DIM + s0 + 8 * g;
#pragma unroll
        for (int ft = 0; ft < 6; ++ft) {
            bf16x8 vf = *(const bf16x8*)(vbase + (size_t)(ft * 16 + col) * T_DIM);
#pragma unroll
            for (int m = 0; m < 3; ++m)
                oacc[m][ft] = __builtin_amdgcn_mfma_f32_16x16x32_bf16(pf[m], vf, oacc[m][ft], 0, 0, 0);
        }
        asm volatile("" ::: "memory");
    }

#pragma unroll
    for (int m = 0; m < 3; ++m) {
        lsum[m] += __shfl_xor(lsum[m], 16, 64);
        lsum[m] += __shfl_xor(lsum[m], 32, 64);
    }
    float wsc = wscale[0];
    float mw[3];
#pragma unroll
    for (int m = 0; m < 3; ++m) mw[m] = tanhf(raw_map[m]) * wsc;

    float fac[3][4];
#pragma unroll
    for (int m = 0; m < 3; ++m)
#pragma unroll
        for (int r = 0; r < 4; ++r)
            fac[m][r] = mw[m] / __shfl(lsum[m], 4 * g + r, 64);

    float av[6][4];
    float ss[4] = {0.f, 0.f, 0.f, 0.f};
#pragma unroll
    for (int ft = 0; ft < 6; ++ft)
#pragma unroll
        for (int r = 0; r < 4; ++r) {
            float v = fac[0][r] * oacc[0][ft][r] + fac[1][r] * oacc[1][ft][r] + fac[2][r] * oacc[2][ft][r];
            av[ft][r] = v;
            ss[r] += v * v;
        }
#pragma unroll
    for (int r = 0; r < 4; ++r) {
        ss[r] += __shfl_xor(ss[r], 1, 64);
        ss[r] += __shfl_xor(ss[r], 2, 64);
        ss[r] += __shfl_xor(ss[r], 4, 64);
        ss[r] += __shfl_xor(ss[r], 8, 64);
        ss[r] = rsqrtf(ss[r] * (1.f / 96.f) + 1e-5f);
    }
#pragma unroll
    for (int ft = 0; ft < 6; ++ft) {
        float sl = subln[ft * 16 + col];
#pragma unroll
        for (int r = 0; r < 4; ++r) {
            int trow = qbase + 4 * g + r;
            outb[(size_t)trow * E_DIM + h * 96 + ft * 16 + col] = f2bf(av[ft][r] * ss[r] * sl);
        }
    }
}

extern "C" void kernel_launch(void* const* d_in, const int* in_sizes, int n_in,
                              void* d_out, int out_size, void* d_ws, size_t ws_size,
                              hipStream_t stream) {
    const float* x       = (const float*)d_in[0];
    const float* cosb    = (const float*)d_in[1];
    const float* sinb    = (const float*)d_in[2];
    const float* q_w     = (const float*)d_in[3];
    const float* k_w     = (const float*)d_in[4];
    const float* v_w     = (const float*)d_in[5];
    const float* out_w   = (const float*)d_in[6];
    const float* raw_map = (const float*)d_in[7];
    const float* wscale  = (const float*)d_in[8];
    const float* subln   = (const float*)d_in[9];
    float* out = (float*)d_out;

    char* ws = (char*)d_ws;
    u16* xb16   = (u16*)(ws);                    // 2048x1536          (6,291,456 B)  [A]
    u16* wqkv16 = (u16*)(ws + 6291456);          // 3072x1536          (9,437,184 B)  [B]
    u16* qkv16  = (u16*)(ws + 15728640);         // 2048x3072          (12,582,912 B) [C]
    u16* wout16 = (u16*)(ws + 28311552);         // 1536x1536          (4,718,592 B)  [D]
    u16* vt16   = (u16*)(ws + 33030144);         // 768x2048           (3,145,728 B)
    // aliases (producer of old region done before reuse):
    u16* qb16  = wqkv16;                         // [B] after QKV gemm
    u16* kb16  = wqkv16 + (size_t)T_DIM * E_DIM; // [B]+6291456
    u16* ab16  = xb16;                           // [A] after QKV gemm

    // f32 -> bf16 conversions
    cvt_bf16<<<3072, 256, 0, stream>>>(x, xb16, 786432);
    cvt_bf16<<<2304, 256, 0, stream>>>(q_w, wqkv16, 589824);
    cvt_bf16<<<1152, 256, 0, stream>>>(k_w, wqkv16 + 2359296, 294912);
    cvt_bf16<<<1152, 256, 0, stream>>>(v_w, wqkv16 + 3538944, 294912);
    cvt_bf16<<<2304, 256, 0, stream>>>(out_w, wout16, 589824);

    // fused QKV projection: [2048,1536] x [3072,1536]^T -> bf16 [2048,3072]
    gemm_mfma<1><<<dim3(3072 / 64, T_DIM / 128), 256, 0, stream>>>(xb16, wqkv16, qkv16, K_DIM, 3072);

    // RoPE + layouts. Q gets hd^-0.5 * log2(e) folded (softmax uses exp2).
    const float qscale = 0.17677669529663687f * 1.4426950408889634f;
    rope_cvt16<<<6144, 256, 0, stream>>>(qkv16, qb16, cosb, sinb, 16, 3072, 0, E_DIM, qscale, 1572864);
    rope_cvt16<<<3072, 256, 0, stream>>>(qkv16, kb16, cosb, sinb, 8, 3072, 1536, 768, 1.f, 786432);
    v_t16<<<6144, 256, 0, stream>>>(qkv16, vt16);

    // attention + combine + RMS + subln -> bf16
    attn_mfma<<<dim3(T_DIM / 16, 16), 64, 0, stream>>>(qb16, kb16, vt16, raw_map, wscale, subln, ab16);

    // output projection: [2048,1536] x [1536,1536]^T -> f32 d_out
    gemm_mfma<0><<<dim3(E_DIM / 64, T_DIM / 128), 256, 0, stream>>>(ab16, wout16, out, K_DIM, E_DIM);
}

// Round 4
// 228.362 us; speedup vs baseline: 12.4387x; 1.1392x over previous
//
#include <hip/hip_runtime.h>
#include <math.h>

#define T_DIM 2048
#define E_DIM 1536
#define K_DIM 1536

typedef unsigned short u16;
typedef unsigned int u32;
typedef __attribute__((ext_vector_type(8))) short bf16x8;
typedef __attribute__((ext_vector_type(4))) float f32x4;

__device__ __forceinline__ u16 f2bf(float x) {
    unsigned u = __float_as_uint(x);
    return (u16)((u + 0x7fffu + ((u >> 16) & 1u)) >> 16);
}
__device__ __forceinline__ float bf2f(u16 x) {
    unsigned u = ((unsigned)x) << 16;
    return __uint_as_float(u);
}

#define GLOAD16(gsrc, ldst)                                                              \
    __builtin_amdgcn_global_load_lds((const __attribute__((address_space(1))) u32*)(gsrc), \
                                     (__attribute__((address_space(3))) u32*)(ldst), 16, 0, 0)

// ---------------- f32 -> bf16 elementwise (4 per thread)
__global__ __launch_bounds__(256) void cvt_bf16(const float* __restrict__ in,
                                                u16* __restrict__ out, int n4) {
    int i = blockIdx.x * 256 + threadIdx.x;
    if (i >= n4) return;
    float4 v = ((const float4*)in)[i];
    ushort4 o = make_ushort4(f2bf(v.x), f2bf(v.y), f2bf(v.z), f2bf(v.w));
    ((ushort4*)out)[i] = o;
}

// ---------------- bf16 MFMA GEMM: C[M,N] = A[M,K] * W[N,K]^T (unchanged)
template <int OUT_BF16>
__global__ __launch_bounds__(256) void gemm_mfma(const u16* __restrict__ A,
                                                 const u16* __restrict__ W,
                                                 void* __restrict__ Cp,
                                                 int K, int ldC) {
    __shared__ __align__(16) u16 As[128 * 64];
    __shared__ __align__(16) u16 Bs[64 * 64];
    const int tid = threadIdx.x;
    const int lane = tid & 63;
    const int wv = tid >> 6;
    const int wr = wv >> 1;
    const int wc = wv & 1;
    const int cl = lane & 15;
    const int g = lane >> 4;
    const int bm = blockIdx.y * 128;
    const int bn = blockIdx.x * 64;

    const char* Ab = (const char*)A;
    const char* Wb = (const char*)W;

    size_t a_src[4];
    int a_dst[4];
#pragma unroll
    for (int is = 0; is < 4; ++is) {
        int b = is * 4096 + wv * 1024 + lane * 16;
        int row = b >> 7;
        int wi = b & 127;
        a_src[is] = (size_t)(bm + row) * (K * 2) + (wi ^ ((row & 7) << 4));
        a_dst[is] = b;
    }
    size_t b_src[2];
    int b_dst[2];
#pragma unroll
    for (int is = 0; is < 2; ++is) {
        int b = is * 4096 + wv * 1024 + lane * 16;
        int row = b >> 7;
        int wi = b & 127;
        b_src[is] = (size_t)(bn + row) * (K * 2) + (wi ^ ((row & 7) << 4));
        b_dst[is] = b;
    }

    f32x4 acc[4][2];
#pragma unroll
    for (int mi = 0; mi < 4; ++mi)
#pragma unroll
        for (int ni = 0; ni < 2; ++ni) acc[mi][ni] = (f32x4){0.f, 0.f, 0.f, 0.f};

    for (int k0b = 0; k0b < K * 2; k0b += 128) {
#pragma unroll
        for (int is = 0; is < 4; ++is)
            GLOAD16(Ab + a_src[is] + k0b, (char*)As + a_dst[is]);
#pragma unroll
        for (int is = 0; is < 2; ++is)
            GLOAD16(Wb + b_src[is] + k0b, (char*)Bs + b_dst[is]);
        __syncthreads();
#pragma unroll
        for (int kk = 0; kk < 2; ++kk) {
            const int co = (kk * 64 + g * 16) ^ ((cl & 7) << 4);
            bf16x8 af[4], bfr[2];
#pragma unroll
            for (int mi = 0; mi < 4; ++mi)
                af[mi] = *(const bf16x8*)((const char*)As + (wr * 64 + mi * 16 + cl) * 128 + co);
#pragma unroll
            for (int ni = 0; ni < 2; ++ni)
                bfr[ni] = *(const bf16x8*)((const char*)Bs + (wc * 32 + ni * 16 + cl) * 128 + co);
#pragma unroll
            for (int mi = 0; mi < 4; ++mi)
#pragma unroll
                for (int ni = 0; ni < 2; ++ni)
                    acc[mi][ni] = __builtin_amdgcn_mfma_f32_16x16x32_bf16(af[mi], bfr[ni], acc[mi][ni], 0, 0, 0);
        }
        __syncthreads();
    }

#pragma unroll
    for (int mi = 0; mi < 4; ++mi)
#pragma unroll
        for (int ni = 0; ni < 2; ++ni)
#pragma unroll
            for (int r = 0; r < 4; ++r) {
                size_t row = bm + wr * 64 + mi * 16 + 4 * g + r;
                size_t col = bn + wc * 32 + ni * 16 + cl;
                if (OUT_BF16)
                    ((u16*)Cp)[row * ldC + col] = f2bf(acc[mi][ni][r]);
                else
                    ((float*)Cp)[row * ldC + col] = acc[mi][ni][r];
            }
}

// ---------------- RoPE (bf16 in/out) + optional scale
__global__ __launch_bounds__(256) void rope_cvt16(const u16* __restrict__ in,
                                                  u16* __restrict__ outb,
                                                  const float* __restrict__ cosb,
                                                  const float* __restrict__ sinb,
                                                  int nh, int inld, int incol0, int outld,
                                                  float scale, int total) {
    int p = blockIdx.x * 256 + threadIdx.x;
    if (p >= total) return;
    int i = p & 15;
    int hh = (p >> 4) % nh;
    int m = ((p >> 4) / nh) % 3;
    int t = p / (16 * nh * 3);
    float c = cosb[t * 16 + i];
    float s = sinb[t * 16 + i];
    size_t ioff = (size_t)t * inld + incol0 + m * (nh * 32) + hh * 32 + 2 * i;
    ushort2 xv = *(const ushort2*)(in + ioff);
    float x1 = bf2f(xv.x), x2 = bf2f(xv.y);
    float o1 = (x1 * c - x2 * s) * scale;
    float o2 = (x1 * s + x2 * c) * scale;
    size_t ooff = (size_t)t * outld + m * (nh * 32) + hh * 32 + 2 * i;
    *(ushort2*)(outb + ooff) = make_ushort2(f2bf(o1), f2bf(o2));
}

// ---------------- V slice transpose: qkv[t][2304+f] -> vt[f][t]
__global__ __launch_bounds__(256) void v_t16(const u16* __restrict__ in, u16* __restrict__ vt) {
    int id = blockIdx.x * 256 + threadIdx.x;
    int t = id & (T_DIM - 1);
    int f = id >> 11;
    vt[(size_t)f * T_DIM + t] = in[(size_t)t * 3072 + 2304 + f];
}

// ---------------- MFMA flash attention, key-split across 4 waves per block.
// No max-subtraction -> partial (O, lsum) over disjoint key ranges are additive;
// waves reduce via LDS tree, wave 0 runs combine+RMS+subln epilogue.
__global__ __launch_bounds__(256, 4) void attn_mfma(const u16* __restrict__ qb,
                                                    const u16* __restrict__ kb,
                                                    const u16* __restrict__ vt,
                                                    const float* __restrict__ raw_map,
                                                    const float* __restrict__ wscale,
                                                    const float* __restrict__ subln,
                                                    u16* __restrict__ outb) {
    __shared__ __align__(16) char smem[21504];   // union: plds (15360 B) / red (21504 B)
    const int tid = threadIdx.x;
    const int lane = tid & 63;
    const int wv = tid >> 6;
    const int col = lane & 15;
    const int g = lane >> 4;
    const int qbase = (127 - (int)blockIdx.x) * 16;   // heaviest blocks first (LPT)
    const int h = blockIdx.y;
    const int kvh = h >> 1;
    const int nchunks = (qbase + 16 + 31) >> 5;

    u16 (*plds)[16][40] = ((u16(*)[16][40])smem) + wv * 3;  // wave-private P tiles
    float (*red)[84] = (float(*)[84])smem;                   // epilogue reduce buffer

    bf16x8 qfrag[3];
#pragma unroll
    for (int m = 0; m < 3; ++m)
        qfrag[m] = *(const bf16x8*)(qb + (size_t)(qbase + col) * E_DIM + m * 512 + h * 32 + 8 * g);

    f32x4 oacc[3][6];
#pragma unroll
    for (int m = 0; m < 3; ++m)
#pragma unroll
        for (int ft = 0; ft < 6; ++ft) oacc[m][ft] = (f32x4){0.f, 0.f, 0.f, 0.f};
    float lsum[3] = {0.f, 0.f, 0.f};

    for (int c = wv; c < nchunks; c += 4) {
        const int s0 = c << 5;
        const bool need_mask = (s0 + 31 > qbase);
#pragma unroll
        for (int m = 0; m < 3; ++m) {
            const u16* kbase = kb + m * 256 + kvh * 32 + 8 * g;
#pragma unroll
            for (int st = 0; st < 2; ++st) {
                bf16x8 kf = *(const bf16x8*)(kbase + (size_t)(s0 + st * 16 + col) * 768);
                f32x4 sv = __builtin_amdgcn_mfma_f32_16x16x32_bf16(
                    kf, qfrag[m], (f32x4){0.f, 0.f, 0.f, 0.f}, 0, 0, 0);
                float p[4];
#pragma unroll
                for (int r = 0; r < 4; ++r) {
                    float x = sv[r];
                    if (need_mask && (s0 + st * 16 + 4 * g + r > qbase + col)) x = -1e30f;
                    p[r] = __builtin_amdgcn_exp2f(x);
                    lsum[m] += p[r];
                }
                *(ushort2*)&plds[m][col][st * 16 + 4 * g]     = make_ushort2(f2bf(p[0]), f2bf(p[1]));
                *(ushort2*)&plds[m][col][st * 16 + 4 * g + 2] = make_ushort2(f2bf(p[2]), f2bf(p[3]));
            }
        }
        asm volatile("s_waitcnt lgkmcnt(0)" ::: "memory");
        bf16x8 pf[3];
#pragma unroll
        for (int m = 0; m < 3; ++m)
            pf[m] = *(const bf16x8*)&plds[m][col][8 * g];
        const u16* vbase = vt + (size_t)(kvh * 96) * T_DIM + s0 + 8 * g;
#pragma unroll
        for (int ft = 0; ft < 6; ++ft) {
            bf16x8 vf = *(const bf16x8*)(vbase + (size_t)(ft * 16 + col) * T_DIM);
#pragma unroll
            for (int m = 0; m < 3; ++m)
                oacc[m][ft] = __builtin_amdgcn_mfma_f32_16x16x32_bf16(pf[m], vf, oacc[m][ft], 0, 0, 0);
        }
        asm volatile("" ::: "memory");
    }

    // ---- cross-wave reduction (additive partials) into wave 0
    __syncthreads();   // plds dead everywhere; red takes over the union
#pragma unroll
    for (int src = 1; src < 4; ++src) {
        if (wv == src) {
            float4* rp = (float4*)red[lane];
#pragma unroll
            for (int m = 0; m < 3; ++m)
#pragma unroll
                for (int ft = 0; ft < 6; ++ft)
                    rp[m * 6 + ft] = make_float4(oacc[m][ft][0], oacc[m][ft][1],
                                                 oacc[m][ft][2], oacc[m][ft][3]);
            red[lane][72] = lsum[0];
            red[lane][73] = lsum[1];
            red[lane][74] = lsum[2];
        }
        __syncthreads();
        if (wv == 0) {
            const float4* rp = (const float4*)red[lane];
#pragma unroll
            for (int m = 0; m < 3; ++m)
#pragma unroll
                for (int ft = 0; ft < 6; ++ft) {
                    float4 a = rp[m * 6 + ft];
                    oacc[m][ft][0] += a.x; oacc[m][ft][1] += a.y;
                    oacc[m][ft][2] += a.z; oacc[m][ft][3] += a.w;
                }
            lsum[0] += red[lane][72];
            lsum[1] += red[lane][73];
            lsum[2] += red[lane][74];
        }
        __syncthreads();
    }
    if (wv != 0) return;

    // ---- epilogue (wave 0): finish row sums, combine ensembles, RMS + subln
#pragma unroll
    for (int m = 0; m < 3; ++m) {
        lsum[m] += __shfl_xor(lsum[m], 16, 64);
        lsum[m] += __shfl_xor(lsum[m], 32, 64);
    }
    float wsc = wscale[0];
    float mw[3];
#pragma unroll
    for (int m = 0; m < 3; ++m) mw[m] = tanhf(raw_map[m]) * wsc;

    float fac[3][4];
#pragma unroll
    for (int m = 0; m < 3; ++m)
#pragma unroll
        for (int r = 0; r < 4; ++r)
            fac[m][r] = mw[m] / __shfl(lsum[m], 4 * g + r, 64);

    float av[6][4];
    float ss[4] = {0.f, 0.f, 0.f, 0.f};
#pragma unroll
    for (int ft = 0; ft < 6; ++ft)
#pragma unroll
        for (int r = 0; r < 4; ++r) {
            float v = fac[0][r] * oacc[0][ft][r] + fac[1][r] * oacc[1][ft][r] + fac[2][r] * oacc[2][ft][r];
            av[ft][r] = v;
            ss[r] += v * v;
        }
#pragma unroll
    for (int r = 0; r < 4; ++r) {
        ss[r] += __shfl_xor(ss[r], 1, 64);
        ss[r] += __shfl_xor(ss[r], 2, 64);
        ss[r] += __shfl_xor(ss[r], 4, 64);
        ss[r] += __shfl_xor(ss[r], 8, 64);
        ss[r] = rsqrtf(ss[r] * (1.f / 96.f) + 1e-5f);
    }
#pragma unroll
    for (int ft = 0; ft < 6; ++ft) {
        float sl = subln[ft * 16 + col];
#pragma unroll
        for (int r = 0; r < 4; ++r) {
            int trow = qbase + 4 * g + r;
            outb[(size_t)trow * E_DIM + h * 96 + ft * 16 + col] = f2bf(av[ft][r] * ss[r] * sl);
        }
    }
}

extern "C" void kernel_launch(void* const* d_in, const int* in_sizes, int n_in,
                              void* d_out, int out_size, void* d_ws, size_t ws_size,
                              hipStream_t stream) {
    const float* x       = (const float*)d_in[0];
    const float* cosb    = (const float*)d_in[1];
    const float* sinb    = (const float*)d_in[2];
    const float* q_w     = (const float*)d_in[3];
    const float* k_w     = (const float*)d_in[4];
    const float* v_w     = (const float*)d_in[5];
    const float* out_w   = (const float*)d_in[6];
    const float* raw_map = (const float*)d_in[7];
    const float* wscale  = (const float*)d_in[8];
    const float* subln   = (const float*)d_in[9];
    float* out = (float*)d_out;

    char* ws = (char*)d_ws;
    u16* xb16   = (u16*)(ws);                    // 2048x1536          (6,291,456 B)  [A]
    u16* wqkv16 = (u16*)(ws + 6291456);          // 3072x1536          (9,437,184 B)  [B]
    u16* qkv16  = (u16*)(ws + 15728640);         // 2048x3072          (12,582,912 B) [C]
    u16* wout16 = (u16*)(ws + 28311552);         // 1536x1536          (4,718,592 B)  [D]
    u16* vt16   = (u16*)(ws + 33030144);         // 768x2048           (3,145,728 B)
    u16* qb16  = wqkv16;                         // [B] after QKV gemm
    u16* kb16  = wqkv16 + (size_t)T_DIM * E_DIM; // [B]+6291456
    u16* ab16  = xb16;                           // [A] after QKV gemm

    // f32 -> bf16 conversions
    cvt_bf16<<<3072, 256, 0, stream>>>(x, xb16, 786432);
    cvt_bf16<<<2304, 256, 0, stream>>>(q_w, wqkv16, 589824);
    cvt_bf16<<<1152, 256, 0, stream>>>(k_w, wqkv16 + 2359296, 294912);
    cvt_bf16<<<1152, 256, 0, stream>>>(v_w, wqkv16 + 3538944, 294912);
    cvt_bf16<<<2304, 256, 0, stream>>>(out_w, wout16, 589824);

    // fused QKV projection: [2048,1536] x [3072,1536]^T -> bf16 [2048,3072]
    gemm_mfma<1><<<dim3(3072 / 64, T_DIM / 128), 256, 0, stream>>>(xb16, wqkv16, qkv16, K_DIM, 3072);

    // RoPE + layouts. Q gets hd^-0.5 * log2(e) folded (softmax uses exp2).
    const float qscale = 0.17677669529663687f * 1.4426950408889634f;
    rope_cvt16<<<6144, 256, 0, stream>>>(qkv16, qb16, cosb, sinb, 16, 3072, 0, E_DIM, qscale, 1572864);
    rope_cvt16<<<3072, 256, 0, stream>>>(qkv16, kb16, cosb, sinb, 8, 3072, 1536, 768, 1.f, 786432);
    v_t16<<<6144, 256, 0, stream>>>(qkv16, vt16);

    // attention + combine + RMS + subln -> bf16
    attn_mfma<<<dim3(T_DIM / 16, 16), 256, 0, stream>>>(qb16, kb16, vt16, raw_map, wscale, subln, ab16);

    // output projection: [2048,1536] x [1536,1536]^T -> f32 d_out
    gemm_mfma<0><<<dim3(E_DIM / 64, T_DIM / 128), 256, 0, stream>>>(ab16, wout16, out, K_DIM, E_DIM);
}

// Round 5
// 207.319 us; speedup vs baseline: 13.7012x; 1.1015x over previous
//
#include <hip/hip_runtime.h>
#include <math.h>

#define T_DIM 2048
#define E_DIM 1536
#define K_DIM 1536

typedef unsigned short u16;
typedef unsigned int u32;
typedef __attribute__((ext_vector_type(8))) short bf16x8;
typedef __attribute__((ext_vector_type(4))) float f32x4;

__device__ __forceinline__ u16 f2bf(float x) {
    unsigned u = __float_as_uint(x);
    return (u16)((u + 0x7fffu + ((u >> 16) & 1u)) >> 16);
}
__device__ __forceinline__ float bf2f(u16 x) {
    unsigned u = ((unsigned)x) << 16;
    return __uint_as_float(u);
}

#define GLOAD16(gsrc, ldst)                                                              \
    __builtin_amdgcn_global_load_lds((const __attribute__((address_space(1))) u32*)(gsrc), \
                                     (__attribute__((address_space(3))) u32*)(ldst), 16, 0, 0)

// ---------------- f32 -> bf16 elementwise (4 per thread)
__global__ __launch_bounds__(256) void cvt_bf16(const float* __restrict__ in,
                                                u16* __restrict__ out, int n4) {
    int i = blockIdx.x * 256 + threadIdx.x;
    if (i >= n4) return;
    float4 v = ((const float4*)in)[i];
    ushort4 o = make_ushort4(f2bf(v.x), f2bf(v.y), f2bf(v.z), f2bf(v.w));
    ((ushort4*)out)[i] = o;
}

// ---------------- bf16 MFMA GEMM: C[M,N] = A[M,K] * W[N,K]^T (unchanged)
template <int OUT_BF16>
__global__ __launch_bounds__(256) void gemm_mfma(const u16* __restrict__ A,
                                                 const u16* __restrict__ W,
                                                 void* __restrict__ Cp,
                                                 int K, int ldC) {
    __shared__ __align__(16) u16 As[128 * 64];
    __shared__ __align__(16) u16 Bs[64 * 64];
    const int tid = threadIdx.x;
    const int lane = tid & 63;
    const int wv = tid >> 6;
    const int wr = wv >> 1;
    const int wc = wv & 1;
    const int cl = lane & 15;
    const int g = lane >> 4;
    const int bm = blockIdx.y * 128;
    const int bn = blockIdx.x * 64;

    const char* Ab = (const char*)A;
    const char* Wb = (const char*)W;

    size_t a_src[4];
    int a_dst[4];
#pragma unroll
    for (int is = 0; is < 4; ++is) {
        int b = is * 4096 + wv * 1024 + lane * 16;
        int row = b >> 7;
        int wi = b & 127;
        a_src[is] = (size_t)(bm + row) * (K * 2) + (wi ^ ((row & 7) << 4));
        a_dst[is] = b;
    }
    size_t b_src[2];
    int b_dst[2];
#pragma unroll
    for (int is = 0; is < 2; ++is) {
        int b = is * 4096 + wv * 1024 + lane * 16;
        int row = b >> 7;
        int wi = b & 127;
        b_src[is] = (size_t)(bn + row) * (K * 2) + (wi ^ ((row & 7) << 4));
        b_dst[is] = b;
    }

    f32x4 acc[4][2];
#pragma unroll
    for (int mi = 0; mi < 4; ++mi)
#pragma unroll
        for (int ni = 0; ni < 2; ++ni) acc[mi][ni] = (f32x4){0.f, 0.f, 0.f, 0.f};

    for (int k0b = 0; k0b < K * 2; k0b += 128) {
#pragma unroll
        for (int is = 0; is < 4; ++is)
            GLOAD16(Ab + a_src[is] + k0b, (char*)As + a_dst[is]);
#pragma unroll
        for (int is = 0; is < 2; ++is)
            GLOAD16(Wb + b_src[is] + k0b, (char*)Bs + b_dst[is]);
        __syncthreads();
#pragma unroll
        for (int kk = 0; kk < 2; ++kk) {
            const int co = (kk * 64 + g * 16) ^ ((cl & 7) << 4);
            bf16x8 af[4], bfr[2];
#pragma unroll
            for (int mi = 0; mi < 4; ++mi)
                af[mi] = *(const bf16x8*)((const char*)As + (wr * 64 + mi * 16 + cl) * 128 + co);
#pragma unroll
            for (int ni = 0; ni < 2; ++ni)
                bfr[ni] = *(const bf16x8*)((const char*)Bs + (wc * 32 + ni * 16 + cl) * 128 + co);
#pragma unroll
            for (int mi = 0; mi < 4; ++mi)
#pragma unroll
                for (int ni = 0; ni < 2; ++ni)
                    acc[mi][ni] = __builtin_amdgcn_mfma_f32_16x16x32_bf16(af[mi], bfr[ni], acc[mi][ni], 0, 0, 0);
        }
        __syncthreads();
    }

#pragma unroll
    for (int mi = 0; mi < 4; ++mi)
#pragma unroll
        for (int ni = 0; ni < 2; ++ni)
#pragma unroll
            for (int r = 0; r < 4; ++r) {
                size_t row = bm + wr * 64 + mi * 16 + 4 * g + r;
                size_t col = bn + wc * 32 + ni * 16 + cl;
                if (OUT_BF16)
                    ((u16*)Cp)[row * ldC + col] = f2bf(acc[mi][ni][r]);
                else
                    ((float*)Cp)[row * ldC + col] = acc[mi][ni][r];
            }
}

// ---------------- Q RoPE (bf16 in/out) + scale, layout-preserving
__global__ __launch_bounds__(256) void rope_cvt16(const u16* __restrict__ in,
                                                  u16* __restrict__ outb,
                                                  const float* __restrict__ cosb,
                                                  const float* __restrict__ sinb,
                                                  int nh, int inld, int incol0, int outld,
                                                  float scale, int total) {
    int p = blockIdx.x * 256 + threadIdx.x;
    if (p >= total) return;
    int i = p & 15;
    int hh = (p >> 4) % nh;
    int m = ((p >> 4) / nh) % 3;
    int t = p / (16 * nh * 3);
    float c = cosb[t * 16 + i];
    float s = sinb[t * 16 + i];
    size_t ioff = (size_t)t * inld + incol0 + m * (nh * 32) + hh * 32 + 2 * i;
    ushort2 xv = *(const ushort2*)(in + ioff);
    float x1 = bf2f(xv.x), x2 = bf2f(xv.y);
    float o1 = (x1 * c - x2 * s) * scale;
    float o2 = (x1 * s + x2 * c) * scale;
    size_t ooff = (size_t)t * outld + m * (nh * 32) + hh * 32 + 2 * i;
    *(ushort2*)(outb + ooff) = make_ushort2(f2bf(o1), f2bf(o2));
}

// ---------------- K RoPE + pack into per-(kvh,chunk) contiguous 6KB tiles
// kpack element (key=c*32+st*16+colk, dim=m*32+d) at
//   ((((kvh*64+c)*3+m)*2+st)*16+colk)*32 + d
__global__ __launch_bounds__(256) void rope_k_pack(const u16* __restrict__ qkv,
                                                   u16* __restrict__ kpack,
                                                   const float* __restrict__ cosb,
                                                   const float* __restrict__ sinb) {
    int p = blockIdx.x * 256 + threadIdx.x;   // total T*3*8*16 = 786432
    int i = p & 15;
    int kvhh = (p >> 4) & 7;
    int m = (p >> 7) % 3;
    int t = (p >> 7) / 3;
    float c = cosb[t * 16 + i];
    float s = sinb[t * 16 + i];
    ushort2 xv = *(const ushort2*)(qkv + (size_t)t * 3072 + 1536 + m * 256 + kvhh * 32 + 2 * i);
    float x1 = bf2f(xv.x), x2 = bf2f(xv.y);
    float o1 = x1 * c - x2 * s;
    float o2 = x1 * s + x2 * c;
    int cch = t >> 5, st = (t >> 4) & 1, colk = t & 15;
    size_t dst = ((((size_t)(kvhh * 64 + cch) * 3 + m) * 2 + st) * 16 + colk) * 32 + 2 * i;
    *(ushort2*)(kpack + dst) = make_ushort2(f2bf(o1), f2bf(o2));
}

// ---------------- V pack: qkv[t][2304 + kvh*96+f] -> vpack[((kvh*64+c)*96+f)*32 + (t&31)]
__global__ __launch_bounds__(256) void v_pack(const u16* __restrict__ qkv,
                                              u16* __restrict__ vpack) {
    int id = blockIdx.x * 256 + threadIdx.x;  // total T*768
    int fq = id % 768;
    int t = id / 768;
    int kvhh = fq / 96, f = fq % 96;
    size_t dst = ((size_t)(kvhh * 64 + (t >> 5)) * 96 + f) * 32 + (t & 31);
    vpack[dst] = qkv[(size_t)t * 3072 + 2304 + fq];
}

// ---------------- MFMA flash attention: packed coalesced K/V tiles + 1-chunk prefetch
__global__ __launch_bounds__(256) void attn_mfma(const u16* __restrict__ qb,
                                                 const u16* __restrict__ kpack,
                                                 const u16* __restrict__ vpack,
                                                 const float* __restrict__ raw_map,
                                                 const float* __restrict__ wscale,
                                                 const float* __restrict__ subln,
                                                 u16* __restrict__ outb) {
    __shared__ __align__(16) char smem[21504];   // union: plds (15360 B) / red (21504 B)
    const int tid = threadIdx.x;
    const int lane = tid & 63;
    const int wv = tid >> 6;
    const int col = lane & 15;
    const int g = lane >> 4;
    const int qbase = (127 - (int)blockIdx.x) * 16;   // heaviest blocks first (LPT)
    const int h = blockIdx.y;
    const int kvh = h >> 1;
    const int nchunks = (qbase + 16 + 31) >> 5;

    u16 (*plds)[16][40] = ((u16(*)[16][40])smem) + wv * 3;  // wave-private P tiles
    float (*red)[84] = (float(*)[84])smem;                   // epilogue reduce buffer

    bf16x8 qfrag[3];
#pragma unroll
    for (int m = 0; m < 3; ++m)
        qfrag[m] = *(const bf16x8*)(qb + (size_t)(qbase + col) * E_DIM + m * 512 + h * 32 + 8 * g);

    f32x4 oacc[3][6];
#pragma unroll
    for (int m = 0; m < 3; ++m)
#pragma unroll
        for (int ft = 0; ft < 6; ++ft) oacc[m][ft] = (f32x4){0.f, 0.f, 0.f, 0.f};
    float lsum[3] = {0.f, 0.f, 0.f};

    // per-lane base within any chunk tile (both kpack and vpack use frag stride 512)
    const size_t tilebase = (size_t)(kvh * 64) * 3072 + (size_t)col * 32 + 8 * g;

    bf16x8 kf[6], vf[6];
    {
        const int c0 = (wv < nchunks) ? wv : 0;
        const u16* kp = kpack + tilebase + (size_t)c0 * 3072;
        const u16* vp = vpack + tilebase + (size_t)c0 * 3072;
#pragma unroll
        for (int u = 0; u < 6; ++u) {
            kf[u] = *(const bf16x8*)(kp + u * 512);
            vf[u] = *(const bf16x8*)(vp + u * 512);
        }
    }

    for (int c = wv; c < nchunks; c += 4) {
        // ---- prefetch next chunk's fragments (clamped; unused if past end)
        const int cn = (c + 4 < nchunks) ? (c + 4) : c;
        const u16* kp = kpack + tilebase + (size_t)cn * 3072;
        const u16* vp = vpack + tilebase + (size_t)cn * 3072;
        bf16x8 kf2[6], vf2[6];
#pragma unroll
        for (int u = 0; u < 6; ++u) {
            kf2[u] = *(const bf16x8*)(kp + u * 512);
            vf2[u] = *(const bf16x8*)(vp + u * 512);
        }

        const int s0 = c << 5;
        const bool need_mask = (s0 + 31 > qbase);
        // ---- S^T = K_tile * Q^T ; exp2; pack P to bf16 via wave-private LDS
#pragma unroll
        for (int m = 0; m < 3; ++m) {
#pragma unroll
            for (int st = 0; st < 2; ++st) {
                f32x4 sv = __builtin_amdgcn_mfma_f32_16x16x32_bf16(
                    kf[m * 2 + st], qfrag[m], (f32x4){0.f, 0.f, 0.f, 0.f}, 0, 0, 0);
                float p[4];
#pragma unroll
                for (int r = 0; r < 4; ++r) {
                    float x = sv[r];
                    if (need_mask && (s0 + st * 16 + 4 * g + r > qbase + col)) x = -1e30f;
                    p[r] = __builtin_amdgcn_exp2f(x);
                    lsum[m] += p[r];
                }
                *(ushort4*)&plds[m][col][st * 16 + 4 * g] =
                    make_ushort4(f2bf(p[0]), f2bf(p[1]), f2bf(p[2]), f2bf(p[3]));
            }
        }
        // compiler inserts lgkmcnt before these reads (exact aliasing on plds)
        bf16x8 pf[3];
#pragma unroll
        for (int m = 0; m < 3; ++m)
            pf[m] = *(const bf16x8*)&plds[m][col][8 * g];
#pragma unroll
        for (int ft = 0; ft < 6; ++ft)
#pragma unroll
            for (int m = 0; m < 3; ++m)
                oacc[m][ft] = __builtin_amdgcn_mfma_f32_16x16x32_bf16(pf[m], vf[ft], oacc[m][ft], 0, 0, 0);

#pragma unroll
        for (int u = 0; u < 6; ++u) { kf[u] = kf2[u]; vf[u] = vf2[u]; }
    }

    // ---- cross-wave reduction (additive partials) into wave 0
    __syncthreads();   // plds dead everywhere; red takes over the union
#pragma unroll
    for (int src = 1; src < 4; ++src) {
        if (wv == src) {
            float4* rp = (float4*)red[lane];
#pragma unroll
            for (int m = 0; m < 3; ++m)
#pragma unroll
                for (int ft = 0; ft < 6; ++ft)
                    rp[m * 6 + ft] = make_float4(oacc[m][ft][0], oacc[m][ft][1],
                                                 oacc[m][ft][2], oacc[m][ft][3]);
            red[lane][72] = lsum[0];
            red[lane][73] = lsum[1];
            red[lane][74] = lsum[2];
        }
        __syncthreads();
        if (wv == 0) {
            const float4* rp = (const float4*)red[lane];
#pragma unroll
            for (int m = 0; m < 3; ++m)
#pragma unroll
                for (int ft = 0; ft < 6; ++ft) {
                    float4 a = rp[m * 6 + ft];
                    oacc[m][ft][0] += a.x; oacc[m][ft][1] += a.y;
                    oacc[m][ft][2] += a.z; oacc[m][ft][3] += a.w;
                }
            lsum[0] += red[lane][72];
            lsum[1] += red[lane][73];
            lsum[2] += red[lane][74];
        }
        __syncthreads();
    }
    if (wv != 0) return;

    // ---- epilogue (wave 0): finish row sums, combine ensembles, RMS + subln
#pragma unroll
    for (int m = 0; m < 3; ++m) {
        lsum[m] += __shfl_xor(lsum[m], 16, 64);
        lsum[m] += __shfl_xor(lsum[m], 32, 64);
    }
    float wsc = wscale[0];
    float mw[3];
#pragma unroll
    for (int m = 0; m < 3; ++m) mw[m] = tanhf(raw_map[m]) * wsc;

    float fac[3][4];
#pragma unroll
    for (int m = 0; m < 3; ++m)
#pragma unroll
        for (int r = 0; r < 4; ++r)
            fac[m][r] = mw[m] / __shfl(lsum[m], 4 * g + r, 64);

    float av[6][4];
    float ss[4] = {0.f, 0.f, 0.f, 0.f};
#pragma unroll
    for (int ft = 0; ft < 6; ++ft)
#pragma unroll
        for (int r = 0; r < 4; ++r) {
            float v = fac[0][r] * oacc[0][ft][r] + fac[1][r] * oacc[1][ft][r] + fac[2][r] * oacc[2][ft][r];
            av[ft][r] = v;
            ss[r] += v * v;
        }
#pragma unroll
    for (int r = 0; r < 4; ++r) {
        ss[r] += __shfl_xor(ss[r], 1, 64);
        ss[r] += __shfl_xor(ss[r], 2, 64);
        ss[r] += __shfl_xor(ss[r], 4, 64);
        ss[r] += __shfl_xor(ss[r], 8, 64);
        ss[r] = rsqrtf(ss[r] * (1.f / 96.f) + 1e-5f);
    }
#pragma unroll
    for (int ft = 0; ft < 6; ++ft) {
        float sl = subln[ft * 16 + col];
#pragma unroll
        for (int r = 0; r < 4; ++r) {
            int trow = qbase + 4 * g + r;
            outb[(size_t)trow * E_DIM + h * 96 + ft * 16 + col] = f2bf(av[ft][r] * ss[r] * sl);
        }
    }
}

extern "C" void kernel_launch(void* const* d_in, const int* in_sizes, int n_in,
                              void* d_out, int out_size, void* d_ws, size_t ws_size,
                              hipStream_t stream) {
    const float* x       = (const float*)d_in[0];
    const float* cosb    = (const float*)d_in[1];
    const float* sinb    = (const float*)d_in[2];
    const float* q_w     = (const float*)d_in[3];
    const float* k_w     = (const float*)d_in[4];
    const float* v_w     = (const float*)d_in[5];
    const float* out_w   = (const float*)d_in[6];
    const float* raw_map = (const float*)d_in[7];
    const float* wscale  = (const float*)d_in[8];
    const float* subln   = (const float*)d_in[9];
    float* out = (float*)d_out;

    char* ws = (char*)d_ws;
    u16* xb16   = (u16*)(ws);                    // 2048x1536          (6,291,456 B)  [A]
    u16* wqkv16 = (u16*)(ws + 6291456);          // 3072x1536          (9,437,184 B)  [B]
    u16* qkv16  = (u16*)(ws + 15728640);         // 2048x3072          (12,582,912 B) [C]
    u16* wout16 = (u16*)(ws + 28311552);         // 1536x1536          (4,718,592 B)  [D]
    u16* vpack  = (u16*)(ws + 33030144);         // 8x64x96x32         (3,145,728 B)
    u16* qb16  = wqkv16;                              // [B] after QKV gemm (6 MB)
    u16* kpack = wqkv16 + (size_t)T_DIM * E_DIM;      // [B]+6MB: 8x64x3x2x16x32 (3 MB)
    u16* ab16  = xb16;                                // [A] after QKV gemm

    // f32 -> bf16 conversions
    cvt_bf16<<<3072, 256, 0, stream>>>(x, xb16, 786432);
    cvt_bf16<<<2304, 256, 0, stream>>>(q_w, wqkv16, 589824);
    cvt_bf16<<<1152, 256, 0, stream>>>(k_w, wqkv16 + 2359296, 294912);
    cvt_bf16<<<1152, 256, 0, stream>>>(v_w, wqkv16 + 3538944, 294912);
    cvt_bf16<<<2304, 256, 0, stream>>>(out_w, wout16, 589824);

    // fused QKV projection: [2048,1536] x [3072,1536]^T -> bf16 [2048,3072]
    gemm_mfma<1><<<dim3(3072 / 64, T_DIM / 128), 256, 0, stream>>>(xb16, wqkv16, qkv16, K_DIM, 3072);

    // RoPE + layouts. Q gets hd^-0.5 * log2(e) folded (softmax uses exp2).
    const float qscale = 0.17677669529663687f * 1.4426950408889634f;
    rope_cvt16<<<6144, 256, 0, stream>>>(qkv16, qb16, cosb, sinb, 16, 3072, 0, E_DIM, qscale, 1572864);
    rope_k_pack<<<3072, 256, 0, stream>>>(qkv16, kpack, cosb, sinb);
    v_pack<<<6144, 256, 0, stream>>>(qkv16, vpack);

    // attention + combine + RMS + subln -> bf16
    attn_mfma<<<dim3(T_DIM / 16, 16), 256, 0, stream>>>(qb16, kpack, vpack, raw_map, wscale, subln, ab16);

    // output projection: [2048,1536] x [1536,1536]^T -> f32 d_out
    gemm_mfma<0><<<dim3(E_DIM / 64, T_DIM / 128), 256, 0, stream>>>(ab16, wout16, out, K_DIM, E_DIM);
}

// Round 6
// 182.874 us; speedup vs baseline: 15.5327x; 1.1337x over previous
//
#include <hip/hip_runtime.h>
#include <hip/hip_bf16.h>
#include <math.h>

#define T_DIM 2048
#define E_DIM 1536
#define K_DIM 1536

typedef unsigned short u16;
typedef unsigned int u32;
typedef __attribute__((ext_vector_type(8))) short bf16x8;
typedef __attribute__((ext_vector_type(4))) float f32x4;

__device__ __forceinline__ u16 f2bf(float x) {
    unsigned u = __float_as_uint(x);
    return (u16)((u + 0x7fffu + ((u >> 16) & 1u)) >> 16);
}
__device__ __forceinline__ float bf2f(u16 x) {
    unsigned u = ((unsigned)x) << 16;
    return __uint_as_float(u);
}

#define GLOAD16(gsrc, ldst)                                                              \
    __builtin_amdgcn_global_load_lds((const __attribute__((address_space(1))) u32*)(gsrc), \
                                     (__attribute__((address_space(3))) u32*)(ldst), 16, 0, 0)

// ---------------- f32 -> bf16 elementwise (4 per thread)
__global__ __launch_bounds__(256) void cvt_bf16(const float* __restrict__ in,
                                                u16* __restrict__ out, int n4) {
    int i = blockIdx.x * 256 + threadIdx.x;
    if (i >= n4) return;
    float4 v = ((const float4*)in)[i];
    ushort4 o = make_ushort4(f2bf(v.x), f2bf(v.y), f2bf(v.z), f2bf(v.w));
    ((ushort4*)out)[i] = o;
}

// ---------------- bf16 MFMA GEMM 128x128 tile: C = A[M,K] * W[N,K]^T  (QKV proj)
// 4 waves (2x2), wave tile 64x64, BK=64. Swizzled global_load_lds staging.
template <int OUT_BF16>
__global__ __launch_bounds__(256) void gemm_mfma_128(const u16* __restrict__ A,
                                                     const u16* __restrict__ W,
                                                     void* __restrict__ Cp,
                                                     int K, int ldC) {
    __shared__ __align__(16) u16 As[128 * 64];
    __shared__ __align__(16) u16 Bs[128 * 64];
    const int tid = threadIdx.x;
    const int lane = tid & 63;
    const int wv = tid >> 6;
    const int wr = wv >> 1;
    const int wc = wv & 1;
    const int cl = lane & 15;
    const int g = lane >> 4;
    const int bm = blockIdx.y * 128;
    const int bn = blockIdx.x * 128;

    const char* Ab = (const char*)A;
    const char* Wb = (const char*)W;

    size_t a_src[4], b_src[4];
    int dst[4];
#pragma unroll
    for (int is = 0; is < 4; ++is) {
        int b = is * 4096 + tid * 16;
        int row = b >> 7;
        int wi = b & 127;
        dst[is] = b;
        a_src[is] = (size_t)(bm + row) * (K * 2) + (wi ^ ((row & 7) << 4));
        b_src[is] = (size_t)(bn + row) * (K * 2) + (wi ^ ((row & 7) << 4));
    }

    f32x4 acc[4][4];
#pragma unroll
    for (int mi = 0; mi < 4; ++mi)
#pragma unroll
        for (int ni = 0; ni < 4; ++ni) acc[mi][ni] = (f32x4){0.f, 0.f, 0.f, 0.f};

    for (int k0b = 0; k0b < K * 2; k0b += 128) {
#pragma unroll
        for (int is = 0; is < 4; ++is)
            GLOAD16(Ab + a_src[is] + k0b, (char*)As + dst[is]);
#pragma unroll
        for (int is = 0; is < 4; ++is)
            GLOAD16(Wb + b_src[is] + k0b, (char*)Bs + dst[is]);
        __syncthreads();
#pragma unroll
        for (int kk = 0; kk < 2; ++kk) {
            const int co = (kk * 64 + g * 16) ^ ((cl & 7) << 4);
            bf16x8 af[4], bfr[4];
#pragma unroll
            for (int mi = 0; mi < 4; ++mi)
                af[mi] = *(const bf16x8*)((const char*)As + (wr * 64 + mi * 16 + cl) * 128 + co);
#pragma unroll
            for (int ni = 0; ni < 4; ++ni)
                bfr[ni] = *(const bf16x8*)((const char*)Bs + (wc * 64 + ni * 16 + cl) * 128 + co);
#pragma unroll
            for (int mi = 0; mi < 4; ++mi)
#pragma unroll
                for (int ni = 0; ni < 4; ++ni)
                    acc[mi][ni] = __builtin_amdgcn_mfma_f32_16x16x32_bf16(af[mi], bfr[ni], acc[mi][ni], 0, 0, 0);
        }
        __syncthreads();
    }

#pragma unroll
    for (int mi = 0; mi < 4; ++mi)
#pragma unroll
        for (int ni = 0; ni < 4; ++ni)
#pragma unroll
            for (int r = 0; r < 4; ++r) {
                size_t row = bm + wr * 64 + mi * 16 + 4 * g + r;
                size_t col = bn + wc * 64 + ni * 16 + cl;
                if (OUT_BF16)
                    ((u16*)Cp)[row * ldC + col] = f2bf(acc[mi][ni][r]);
                else
                    ((float*)Cp)[row * ldC + col] = acc[mi][ni][r];
            }
}

// ---------------- bf16 MFMA GEMM 128x64 tile (output projection; 384 blocks)
template <int OUT_BF16>
__global__ __launch_bounds__(256) void gemm_mfma(const u16* __restrict__ A,
                                                 const u16* __restrict__ W,
                                                 void* __restrict__ Cp,
                                                 int K, int ldC) {
    __shared__ __align__(16) u16 As[128 * 64];
    __shared__ __align__(16) u16 Bs[64 * 64];
    const int tid = threadIdx.x;
    const int lane = tid & 63;
    const int wv = tid >> 6;
    const int wr = wv >> 1;
    const int wc = wv & 1;
    const int cl = lane & 15;
    const int g = lane >> 4;
    const int bm = blockIdx.y * 128;
    const int bn = blockIdx.x * 64;

    const char* Ab = (const char*)A;
    const char* Wb = (const char*)W;

    size_t a_src[4];
    int a_dst[4];
#pragma unroll
    for (int is = 0; is < 4; ++is) {
        int b = is * 4096 + wv * 1024 + lane * 16;
        int row = b >> 7;
        int wi = b & 127;
        a_src[is] = (size_t)(bm + row) * (K * 2) + (wi ^ ((row & 7) << 4));
        a_dst[is] = b;
    }
    size_t b_src[2];
    int b_dst[2];
#pragma unroll
    for (int is = 0; is < 2; ++is) {
        int b = is * 4096 + wv * 1024 + lane * 16;
        int row = b >> 7;
        int wi = b & 127;
        b_src[is] = (size_t)(bn + row) * (K * 2) + (wi ^ ((row & 7) << 4));
        b_dst[is] = b;
    }

    f32x4 acc[4][2];
#pragma unroll
    for (int mi = 0; mi < 4; ++mi)
#pragma unroll
        for (int ni = 0; ni < 2; ++ni) acc[mi][ni] = (f32x4){0.f, 0.f, 0.f, 0.f};

    for (int k0b = 0; k0b < K * 2; k0b += 128) {
#pragma unroll
        for (int is = 0; is < 4; ++is)
            GLOAD16(Ab + a_src[is] + k0b, (char*)As + a_dst[is]);
#pragma unroll
        for (int is = 0; is < 2; ++is)
            GLOAD16(Wb + b_src[is] + k0b, (char*)Bs + b_dst[is]);
        __syncthreads();
#pragma unroll
        for (int kk = 0; kk < 2; ++kk) {
            const int co = (kk * 64 + g * 16) ^ ((cl & 7) << 4);
            bf16x8 af[4], bfr[2];
#pragma unroll
            for (int mi = 0; mi < 4; ++mi)
                af[mi] = *(const bf16x8*)((const char*)As + (wr * 64 + mi * 16 + cl) * 128 + co);
#pragma unroll
            for (int ni = 0; ni < 2; ++ni)
                bfr[ni] = *(const bf16x8*)((const char*)Bs + (wc * 32 + ni * 16 + cl) * 128 + co);
#pragma unroll
            for (int mi = 0; mi < 4; ++mi)
#pragma unroll
                for (int ni = 0; ni < 2; ++ni)
                    acc[mi][ni] = __builtin_amdgcn_mfma_f32_16x16x32_bf16(af[mi], bfr[ni], acc[mi][ni], 0, 0, 0);
        }
        __syncthreads();
    }

#pragma unroll
    for (int mi = 0; mi < 4; ++mi)
#pragma unroll
        for (int ni = 0; ni < 2; ++ni)
#pragma unroll
            for (int r = 0; r < 4; ++r) {
                size_t row = bm + wr * 64 + mi * 16 + 4 * g + r;
                size_t col = bn + wc * 32 + ni * 16 + cl;
                if (OUT_BF16)
                    ((u16*)Cp)[row * ldC + col] = f2bf(acc[mi][ni][r]);
                else
                    ((float*)Cp)[row * ldC + col] = acc[mi][ni][r];
            }
}

// ---------------- Q RoPE (bf16 in/out) + scale, layout-preserving
__global__ __launch_bounds__(256) void rope_cvt16(const u16* __restrict__ in,
                                                  u16* __restrict__ outb,
                                                  const float* __restrict__ cosb,
                                                  const float* __restrict__ sinb,
                                                  int nh, int inld, int incol0, int outld,
                                                  float scale, int total) {
    int p = blockIdx.x * 256 + threadIdx.x;
    if (p >= total) return;
    int i = p & 15;
    int hh = (p >> 4) % nh;
    int m = ((p >> 4) / nh) % 3;
    int t = p / (16 * nh * 3);
    float c = cosb[t * 16 + i];
    float s = sinb[t * 16 + i];
    size_t ioff = (size_t)t * inld + incol0 + m * (nh * 32) + hh * 32 + 2 * i;
    ushort2 xv = *(const ushort2*)(in + ioff);
    float x1 = bf2f(xv.x), x2 = bf2f(xv.y);
    float o1 = (x1 * c - x2 * s) * scale;
    float o2 = (x1 * s + x2 * c) * scale;
    size_t ooff = (size_t)t * outld + m * (nh * 32) + hh * 32 + 2 * i;
    *(ushort2*)(outb + ooff) = make_ushort2(f2bf(o1), f2bf(o2));
}

// ---------------- K RoPE + pack into per-(kvh,chunk) contiguous 6KB tiles
__global__ __launch_bounds__(256) void rope_k_pack(const u16* __restrict__ qkv,
                                                   u16* __restrict__ kpack,
                                                   const float* __restrict__ cosb,
                                                   const float* __restrict__ sinb) {
    int p = blockIdx.x * 256 + threadIdx.x;   // total T*3*8*16 = 786432
    int i = p & 15;
    int kvhh = (p >> 4) & 7;
    int m = (p >> 7) % 3;
    int t = (p >> 7) / 3;
    float c = cosb[t * 16 + i];
    float s = sinb[t * 16 + i];
    ushort2 xv = *(const ushort2*)(qkv + (size_t)t * 3072 + 1536 + m * 256 + kvhh * 32 + 2 * i);
    float x1 = bf2f(xv.x), x2 = bf2f(xv.y);
    float o1 = x1 * c - x2 * s;
    float o2 = x1 * s + x2 * c;
    int cch = t >> 5, st = (t >> 4) & 1, colk = t & 15;
    size_t dst = ((((size_t)(kvhh * 64 + cch) * 3 + m) * 2 + st) * 16 + colk) * 32 + 2 * i;
    *(ushort2*)(kpack + dst) = make_ushort2(f2bf(o1), f2bf(o2));
}

// ---------------- V pack: qkv[t][2304 + kvh*96+f] -> vpack[((kvh*64+c)*96+f)*32 + (t&31)]
__global__ __launch_bounds__(256) void v_pack(const u16* __restrict__ qkv,
                                              u16* __restrict__ vpack) {
    int id = blockIdx.x * 256 + threadIdx.x;  // total T*768
    int fq = id % 768;
    int t = id / 768;
    int kvhh = fq / 96, f = fq % 96;
    size_t dst = ((size_t)(kvhh * 64 + (t >> 5)) * 96 + f) * 32 + (t & 31);
    vpack[dst] = qkv[(size_t)t * 3072 + 2304 + fq];
}

// ---------------- MFMA flash attention.
// Mask-free steady loop (only chunk nchunks-1 crosses the diagonal);
// wave-uniform scalar chunk pointers; packed cvt for P->bf16; no reg prefetch.
__global__ __launch_bounds__(256) void attn_mfma(const u16* __restrict__ qb,
                                                 const u16* __restrict__ kpack,
                                                 const u16* __restrict__ vpack,
                                                 const float* __restrict__ raw_map,
                                                 const float* __restrict__ wscale,
                                                 const float* __restrict__ subln,
                                                 u16* __restrict__ outb) {
    __shared__ __align__(16) char smem[21504];   // union: plds (15360 B) / red (21504 B)
    const int tid = threadIdx.x;
    const int lane = tid & 63;
    const int wv = tid >> 6;
    const int col = lane & 15;
    const int g = lane >> 4;
    const int qbase = (127 - (int)blockIdx.x) * 16;   // heaviest blocks first (LPT)
    const int h = blockIdx.y;
    const int kvh = h >> 1;
    const int nchunks = (qbase + 16 + 31) >> 5;
    const int nfull = nchunks - 1;                    // mask-free chunks

    u16 (*plds)[16][40] = ((u16(*)[16][40])smem) + wv * 3;  // wave-private P tiles
    float (*red)[84] = (float(*)[84])smem;                   // epilogue reduce buffer

    bf16x8 qfrag[3];
#pragma unroll
    for (int m = 0; m < 3; ++m)
        qfrag[m] = *(const bf16x8*)(qb + (size_t)(qbase + col) * E_DIM + m * 512 + h * 32 + 8 * g);

    f32x4 oacc[3][6];
#pragma unroll
    for (int m = 0; m < 3; ++m)
#pragma unroll
        for (int ft = 0; ft < 6; ++ft) oacc[m][ft] = (f32x4){0.f, 0.f, 0.f, 0.f};
    float lsum[3] = {0.f, 0.f, 0.f};

    const int laneoff = col * 32 + 8 * g;             // fixed per-lane element offset in a tile
    const u16* kt = kpack + (size_t)(kvh * 64 + wv) * 3072;
    const u16* vt = vpack + (size_t)(kvh * 64 + wv) * 3072;

    // ---- steady state: no causal masking
    for (int c = wv; c < nfull; c += 4) {
        bf16x8 kf[6], vf[6];
#pragma unroll
        for (int u = 0; u < 6; ++u) kf[u] = *(const bf16x8*)(kt + laneoff + u * 512);
#pragma unroll
        for (int u = 0; u < 6; ++u) vf[u] = *(const bf16x8*)(vt + laneoff + u * 512);
        kt += 4 * 3072;
        vt += 4 * 3072;

#pragma unroll
        for (int m = 0; m < 3; ++m) {
#pragma unroll
            for (int st = 0; st < 2; ++st) {
                f32x4 sv = __builtin_amdgcn_mfma_f32_16x16x32_bf16(
                    kf[m * 2 + st], qfrag[m], (f32x4){0.f, 0.f, 0.f, 0.f}, 0, 0, 0);
                float p0 = __builtin_amdgcn_exp2f(sv[0]);
                float p1 = __builtin_amdgcn_exp2f(sv[1]);
                float p2 = __builtin_amdgcn_exp2f(sv[2]);
                float p3 = __builtin_amdgcn_exp2f(sv[3]);
                lsum[m] += (p0 + p1) + (p2 + p3);
                __hip_bfloat162 b01 = __float22bfloat162_rn(make_float2(p0, p1));
                __hip_bfloat162 b23 = __float22bfloat162_rn(make_float2(p2, p3));
                uint2 w;
                w.x = *(u32*)&b01;
                w.y = *(u32*)&b23;
                *(uint2*)&plds[m][col][st * 16 + 4 * g] = w;
            }
        }
        bf16x8 pf[3];
#pragma unroll
        for (int m = 0; m < 3; ++m)
            pf[m] = *(const bf16x8*)&plds[m][col][8 * g];
#pragma unroll
        for (int ft = 0; ft < 6; ++ft)
#pragma unroll
            for (int m = 0; m < 3; ++m)
                oacc[m][ft] = __builtin_amdgcn_mfma_f32_16x16x32_bf16(pf[m], vf[ft], oacc[m][ft], 0, 0, 0);
    }

    // ---- boundary chunk (the only one needing the causal mask)
    if ((nfull & 3) == wv) {
        const int s0 = nfull << 5;
        const u16* ktm = kpack + (size_t)(kvh * 64 + nfull) * 3072 + laneoff;
        const u16* vtm = vpack + (size_t)(kvh * 64 + nfull) * 3072 + laneoff;
        bf16x8 kf[6], vf[6];
#pragma unroll
        for (int u = 0; u < 6; ++u) kf[u] = *(const bf16x8*)(ktm + u * 512);
#pragma unroll
        for (int u = 0; u < 6; ++u) vf[u] = *(const bf16x8*)(vtm + u * 512);

#pragma unroll
        for (int m = 0; m < 3; ++m) {
#pragma unroll
            for (int st = 0; st < 2; ++st) {
                f32x4 sv = __builtin_amdgcn_mfma_f32_16x16x32_bf16(
                    kf[m * 2 + st], qfrag[m], (f32x4){0.f, 0.f, 0.f, 0.f}, 0, 0, 0);
                float p[4];
#pragma unroll
                for (int r = 0; r < 4; ++r) {
                    float x = sv[r];
                    if (s0 + st * 16 + 4 * g + r > qbase + col) x = -1e30f;
                    p[r] = __builtin_amdgcn_exp2f(x);
                    lsum[m] += p[r];
                }
                __hip_bfloat162 b01 = __float22bfloat162_rn(make_float2(p[0], p[1]));
                __hip_bfloat162 b23 = __float22bfloat162_rn(make_float2(p[2], p[3]));
                uint2 w;
                w.x = *(u32*)&b01;
                w.y = *(u32*)&b23;
                *(uint2*)&plds[m][col][st * 16 + 4 * g] = w;
            }
        }
        bf16x8 pf[3];
#pragma unroll
        for (int m = 0; m < 3; ++m)
            pf[m] = *(const bf16x8*)&plds[m][col][8 * g];
#pragma unroll
        for (int ft = 0; ft < 6; ++ft)
#pragma unroll
            for (int m = 0; m < 3; ++m)
                oacc[m][ft] = __builtin_amdgcn_mfma_f32_16x16x32_bf16(pf[m], vf[ft], oacc[m][ft], 0, 0, 0);
    }

    // ---- cross-wave reduction (additive partials) into wave 0
    __syncthreads();   // plds dead everywhere; red takes over the union
#pragma unroll
    for (int src = 1; src < 4; ++src) {
        if (wv == src) {
            float4* rp = (float4*)red[lane];
#pragma unroll
            for (int m = 0; m < 3; ++m)
#pragma unroll
                for (int ft = 0; ft < 6; ++ft)
                    rp[m * 6 + ft] = make_float4(oacc[m][ft][0], oacc[m][ft][1],
                                                 oacc[m][ft][2], oacc[m][ft][3]);
            red[lane][72] = lsum[0];
            red[lane][73] = lsum[1];
            red[lane][74] = lsum[2];
        }
        __syncthreads();
        if (wv == 0) {
            const float4* rp = (const float4*)red[lane];
#pragma unroll
            for (int m = 0; m < 3; ++m)
#pragma unroll
                for (int ft = 0; ft < 6; ++ft) {
                    float4 a = rp[m * 6 + ft];
                    oacc[m][ft][0] += a.x; oacc[m][ft][1] += a.y;
                    oacc[m][ft][2] += a.z; oacc[m][ft][3] += a.w;
                }
            lsum[0] += red[lane][72];
            lsum[1] += red[lane][73];
            lsum[2] += red[lane][74];
        }
        __syncthreads();
    }
    if (wv != 0) return;

    // ---- epilogue (wave 0): finish row sums, combine ensembles, RMS + subln
#pragma unroll
    for (int m = 0; m < 3; ++m) {
        lsum[m] += __shfl_xor(lsum[m], 16, 64);
        lsum[m] += __shfl_xor(lsum[m], 32, 64);
    }
    float wsc = wscale[0];
    float mw[3];
#pragma unroll
    for (int m = 0; m < 3; ++m) mw[m] = tanhf(raw_map[m]) * wsc;

    float fac[3][4];
#pragma unroll
    for (int m = 0; m < 3; ++m)
#pragma unroll
        for (int r = 0; r < 4; ++r)
            fac[m][r] = mw[m] / __shfl(lsum[m], 4 * g + r, 64);

    float av[6][4];
    float ss[4] = {0.f, 0.f, 0.f, 0.f};
#pragma unroll
    for (int ft = 0; ft < 6; ++ft)
#pragma unroll
        for (int r = 0; r < 4; ++r) {
            float v = fac[0][r] * oacc[0][ft][r] + fac[1][r] * oacc[1][ft][r] + fac[2][r] * oacc[2][ft][r];
            av[ft][r] = v;
            ss[r] += v * v;
        }
#pragma unroll
    for (int r = 0; r < 4; ++r) {
        ss[r] += __shfl_xor(ss[r], 1, 64);
        ss[r] += __shfl_xor(ss[r], 2, 64);
        ss[r] += __shfl_xor(ss[r], 4, 64);
        ss[r] += __shfl_xor(ss[r], 8, 64);
        ss[r] = rsqrtf(ss[r] * (1.f / 96.f) + 1e-5f);
    }
#pragma unroll
    for (int ft = 0; ft < 6; ++ft) {
        float sl = subln[ft * 16 + col];
#pragma unroll
        for (int r = 0; r < 4; ++r) {
            int trow = qbase + 4 * g + r;
            outb[(size_t)trow * E_DIM + h * 96 + ft * 16 + col] = f2bf(av[ft][r] * ss[r] * sl);
        }
    }
}

extern "C" void kernel_launch(void* const* d_in, const int* in_sizes, int n_in,
                              void* d_out, int out_size, void* d_ws, size_t ws_size,
                              hipStream_t stream) {
    const float* x       = (const float*)d_in[0];
    const float* cosb    = (const float*)d_in[1];
    const float* sinb    = (const float*)d_in[2];
    const float* q_w     = (const float*)d_in[3];
    const float* k_w     = (const float*)d_in[4];
    const float* v_w     = (const float*)d_in[5];
    const float* out_w   = (const float*)d_in[6];
    const float* raw_map = (const float*)d_in[7];
    const float* wscale  = (const float*)d_in[8];
    const float* subln   = (const float*)d_in[9];
    float* out = (float*)d_out;

    char* ws = (char*)d_ws;
    u16* xb16   = (u16*)(ws);                    // 2048x1536          (6,291,456 B)  [A]
    u16* wqkv16 = (u16*)(ws + 6291456);          // 3072x1536          (9,437,184 B)  [B]
    u16* qkv16  = (u16*)(ws + 15728640);         // 2048x3072          (12,582,912 B) [C]
    u16* wout16 = (u16*)(ws + 28311552);         // 1536x1536          (4,718,592 B)  [D]
    u16* vpack  = (u16*)(ws + 33030144);         // 8x64x96x32         (3,145,728 B)
    u16* qb16  = wqkv16;                              // [B] after QKV gemm (6 MB)
    u16* kpack = wqkv16 + (size_t)T_DIM * E_DIM;      // [B]+6MB: 8x64x3x2x16x32 (3 MB)
    u16* ab16  = xb16;                                // [A] after QKV gemm

    // f32 -> bf16 conversions
    cvt_bf16<<<3072, 256, 0, stream>>>(x, xb16, 786432);
    cvt_bf16<<<2304, 256, 0, stream>>>(q_w, wqkv16, 589824);
    cvt_bf16<<<1152, 256, 0, stream>>>(k_w, wqkv16 + 2359296, 294912);
    cvt_bf16<<<1152, 256, 0, stream>>>(v_w, wqkv16 + 3538944, 294912);
    cvt_bf16<<<2304, 256, 0, stream>>>(out_w, wout16, 589824);

    // fused QKV projection: [2048,1536] x [3072,1536]^T -> bf16 [2048,3072]
    gemm_mfma_128<1><<<dim3(3072 / 128, T_DIM / 128), 256, 0, stream>>>(xb16, wqkv16, qkv16, K_DIM, 3072);

    // RoPE + layouts. Q gets hd^-0.5 * log2(e) folded (softmax uses exp2).
    const float qscale = 0.17677669529663687f * 1.4426950408889634f;
    rope_cvt16<<<6144, 256, 0, stream>>>(qkv16, qb16, cosb, sinb, 16, 3072, 0, E_DIM, qscale, 1572864);
    rope_k_pack<<<3072, 256, 0, stream>>>(qkv16, kpack, cosb, sinb);
    v_pack<<<6144, 256, 0, stream>>>(qkv16, vpack);

    // attention + combine + RMS + subln -> bf16
    attn_mfma<<<dim3(T_DIM / 16, 16), 256, 0, stream>>>(qb16, kpack, vpack, raw_map, wscale, subln, ab16);

    // output projection: [2048,1536] x [1536,1536]^T -> f32 d_out
    gemm_mfma<0><<<dim3(E_DIM / 64, T_DIM / 128), 256, 0, stream>>>(ab16, wout16, out, K_DIM, E_DIM);
}

// Round 7
// 174.550 us; speedup vs baseline: 16.2734x; 1.0477x over previous
//
#include <hip/hip_runtime.h>
#include <hip/hip_bf16.h>
#include <math.h>

#define T_DIM 2048
#define E_DIM 1536
#define K_DIM 1536

typedef unsigned short u16;
typedef unsigned int u32;
typedef __attribute__((ext_vector_type(8))) short bf16x8;
typedef __attribute__((ext_vector_type(4))) float f32x4;

__device__ __forceinline__ u16 f2bf(float x) {
    unsigned u = __float_as_uint(x);
    return (u16)((u + 0x7fffu + ((u >> 16) & 1u)) >> 16);
}

#define GLOAD16(gsrc, ldst)                                                              \
    __builtin_amdgcn_global_load_lds((const __attribute__((address_space(1))) u32*)(gsrc), \
                                     (__attribute__((address_space(3))) u32*)(ldst), 16, 0, 0)

// ---------------- f32 -> bf16 elementwise (4 per thread)
__global__ __launch_bounds__(256) void cvt_bf16(const float* __restrict__ in,
                                                u16* __restrict__ out, int n4) {
    int i = blockIdx.x * 256 + threadIdx.x;
    if (i >= n4) return;
    float4 v = ((const float4*)in)[i];
    ushort4 o = make_ushort4(f2bf(v.x), f2bf(v.y), f2bf(v.z), f2bf(v.w));
    ((ushort4*)out)[i] = o;
}

// ---------------- fused QKV GEMM: C = x[2048,1536] * Wqkv[3072,1536]^T, epilogue
// applies interleaved RoPE (Q: + hd^-0.5*log2e scale; K: none) and writes directly
// to qb16 / kpack / vpack layouts. Region is block-uniform by bn.
__global__ __launch_bounds__(256) void gemm_qkv_fused(const u16* __restrict__ A,
                                                      const u16* __restrict__ W,
                                                      const float* __restrict__ cosb,
                                                      const float* __restrict__ sinb,
                                                      u16* __restrict__ qb16,
                                                      u16* __restrict__ kpack,
                                                      u16* __restrict__ vpack,
                                                      float qscale) {
    const int K = K_DIM;
    __shared__ __align__(16) u16 As[128 * 64];
    __shared__ __align__(16) u16 Bs[64 * 64];
    const int tid = threadIdx.x;
    const int lane = tid & 63;
    const int wv = tid >> 6;
    const int wr = wv >> 1;
    const int wc = wv & 1;
    const int cl = lane & 15;
    const int g = lane >> 4;
    const int bm = blockIdx.y * 128;
    const int bn = blockIdx.x * 64;

    const char* Ab = (const char*)A;
    const char* Wb = (const char*)W;

    size_t a_src[4];
    int a_dst[4];
#pragma unroll
    for (int is = 0; is < 4; ++is) {
        int b = is * 4096 + wv * 1024 + lane * 16;
        int row = b >> 7;
        int wi = b & 127;
        a_src[is] = (size_t)(bm + row) * (K * 2) + (wi ^ ((row & 7) << 4));
        a_dst[is] = b;
    }
    size_t b_src[2];
    int b_dst[2];
#pragma unroll
    for (int is = 0; is < 2; ++is) {
        int b = is * 4096 + wv * 1024 + lane * 16;
        int row = b >> 7;
        int wi = b & 127;
        b_src[is] = (size_t)(bn + row) * (K * 2) + (wi ^ ((row & 7) << 4));
        b_dst[is] = b;
    }

    f32x4 acc[4][2];
#pragma unroll
    for (int mi = 0; mi < 4; ++mi)
#pragma unroll
        for (int ni = 0; ni < 2; ++ni) acc[mi][ni] = (f32x4){0.f, 0.f, 0.f, 0.f};

    for (int k0b = 0; k0b < K * 2; k0b += 128) {
#pragma unroll
        for (int is = 0; is < 4; ++is)
            GLOAD16(Ab + a_src[is] + k0b, (char*)As + a_dst[is]);
#pragma unroll
        for (int is = 0; is < 2; ++is)
            GLOAD16(Wb + b_src[is] + k0b, (char*)Bs + b_dst[is]);
        __syncthreads();
#pragma unroll
        for (int kk = 0; kk < 2; ++kk) {
            const int co = (kk * 64 + g * 16) ^ ((cl & 7) << 4);
            bf16x8 af[4], bfr[2];
#pragma unroll
            for (int mi = 0; mi < 4; ++mi)
                af[mi] = *(const bf16x8*)((const char*)As + (wr * 64 + mi * 16 + cl) * 128 + co);
#pragma unroll
            for (int ni = 0; ni < 2; ++ni)
                bfr[ni] = *(const bf16x8*)((const char*)Bs + (wc * 32 + ni * 16 + cl) * 128 + co);
#pragma unroll
            for (int mi = 0; mi < 4; ++mi)
#pragma unroll
                for (int ni = 0; ni < 2; ++ni)
                    acc[mi][ni] = __builtin_amdgcn_mfma_f32_16x16x32_bf16(af[mi], bfr[ni], acc[mi][ni], 0, 0, 0);
        }
        __syncthreads();
    }

    // ---- fused epilogue: RoPE + pack. col parity partner lives in lane^1.
    if (bn < 1536) {
        // Q region: rope + qscale -> qb16[t][c]
#pragma unroll
        for (int mi = 0; mi < 4; ++mi)
#pragma unroll
            for (int ni = 0; ni < 2; ++ni)
#pragma unroll
                for (int r = 0; r < 4; ++r) {
                    int trow = bm + wr * 64 + mi * 16 + 4 * g + r;
                    int c = bn + wc * 32 + ni * 16 + cl;
                    float v = acc[mi][ni][r];
                    float pv = __shfl_xor(v, 1, 64);
                    int i = (c & 31) >> 1;
                    float cs = cosb[trow * 16 + i];
                    float sn = sinb[trow * 16 + i];
                    float o = v * cs + ((c & 1) ? pv * sn : -pv * sn);
                    qb16[(size_t)trow * E_DIM + c] = f2bf(o * qscale);
                }
    } else if (bn < 2304) {
        // K region: rope -> kpack
#pragma unroll
        for (int mi = 0; mi < 4; ++mi)
#pragma unroll
            for (int ni = 0; ni < 2; ++ni)
#pragma unroll
                for (int r = 0; r < 4; ++r) {
                    int trow = bm + wr * 64 + mi * 16 + 4 * g + r;
                    int c = bn + wc * 32 + ni * 16 + cl;
                    float v = acc[mi][ni][r];
                    float pv = __shfl_xor(v, 1, 64);
                    int i = (c & 31) >> 1;
                    float cs = cosb[trow * 16 + i];
                    float sn = sinb[trow * 16 + i];
                    float o = v * cs + ((c & 1) ? pv * sn : -pv * sn);
                    int ck = c - 1536;
                    int m = ck >> 8;
                    int rem = ck & 255;
                    int kvhh = rem >> 5;
                    int d = rem & 31;
                    int cch = trow >> 5, st2 = (trow >> 4) & 1, colk = trow & 15;
                    size_t dst = ((((size_t)(kvhh * 64 + cch) * 3 + m) * 2 + st2) * 16 + colk) * 32 + d;
                    kpack[dst] = f2bf(o);
                }
    } else {
        // V region: plain pack
#pragma unroll
        for (int mi = 0; mi < 4; ++mi)
#pragma unroll
            for (int ni = 0; ni < 2; ++ni)
#pragma unroll
                for (int r = 0; r < 4; ++r) {
                    int trow = bm + wr * 64 + mi * 16 + 4 * g + r;
                    int c = bn + wc * 32 + ni * 16 + cl;
                    int fq = c - 2304;
                    int kvhh = fq / 96;
                    int f = fq - kvhh * 96;
                    size_t dst = ((size_t)(kvhh * 64 + (trow >> 5)) * 96 + f) * 32 + (trow & 31);
                    vpack[dst] = f2bf(acc[mi][ni][r]);
                }
    }
}

// ---------------- bf16 MFMA GEMM 128x64 tile (output projection)
template <int OUT_BF16>
__global__ __launch_bounds__(256) void gemm_mfma(const u16* __restrict__ A,
                                                 const u16* __restrict__ W,
                                                 void* __restrict__ Cp,
                                                 int K, int ldC) {
    __shared__ __align__(16) u16 As[128 * 64];
    __shared__ __align__(16) u16 Bs[64 * 64];
    const int tid = threadIdx.x;
    const int lane = tid & 63;
    const int wv = tid >> 6;
    const int wr = wv >> 1;
    const int wc = wv & 1;
    const int cl = lane & 15;
    const int g = lane >> 4;
    const int bm = blockIdx.y * 128;
    const int bn = blockIdx.x * 64;

    const char* Ab = (const char*)A;
    const char* Wb = (const char*)W;

    size_t a_src[4];
    int a_dst[4];
#pragma unroll
    for (int is = 0; is < 4; ++is) {
        int b = is * 4096 + wv * 1024 + lane * 16;
        int row = b >> 7;
        int wi = b & 127;
        a_src[is] = (size_t)(bm + row) * (K * 2) + (wi ^ ((row & 7) << 4));
        a_dst[is] = b;
    }
    size_t b_src[2];
    int b_dst[2];
#pragma unroll
    for (int is = 0; is < 2; ++is) {
        int b = is * 4096 + wv * 1024 + lane * 16;
        int row = b >> 7;
        int wi = b & 127;
        b_src[is] = (size_t)(bn + row) * (K * 2) + (wi ^ ((row & 7) << 4));
        b_dst[is] = b;
    }

    f32x4 acc[4][2];
#pragma unroll
    for (int mi = 0; mi < 4; ++mi)
#pragma unroll
        for (int ni = 0; ni < 2; ++ni) acc[mi][ni] = (f32x4){0.f, 0.f, 0.f, 0.f};

    for (int k0b = 0; k0b < K * 2; k0b += 128) {
#pragma unroll
        for (int is = 0; is < 4; ++is)
            GLOAD16(Ab + a_src[is] + k0b, (char*)As + a_dst[is]);
#pragma unroll
        for (int is = 0; is < 2; ++is)
            GLOAD16(Wb + b_src[is] + k0b, (char*)Bs + b_dst[is]);
        __syncthreads();
#pragma unroll
        for (int kk = 0; kk < 2; ++kk) {
            const int co = (kk * 64 + g * 16) ^ ((cl & 7) << 4);
            bf16x8 af[4], bfr[2];
#pragma unroll
            for (int mi = 0; mi < 4; ++mi)
                af[mi] = *(const bf16x8*)((const char*)As + (wr * 64 + mi * 16 + cl) * 128 + co);
#pragma unroll
            for (int ni = 0; ni < 2; ++ni)
                bfr[ni] = *(const bf16x8*)((const char*)Bs + (wc * 32 + ni * 16 + cl) * 128 + co);
#pragma unroll
            for (int mi = 0; mi < 4; ++mi)
#pragma unroll
                for (int ni = 0; ni < 2; ++ni)
                    acc[mi][ni] = __builtin_amdgcn_mfma_f32_16x16x32_bf16(af[mi], bfr[ni], acc[mi][ni], 0, 0, 0);
        }
        __syncthreads();
    }

#pragma unroll
    for (int mi = 0; mi < 4; ++mi)
#pragma unroll
        for (int ni = 0; ni < 2; ++ni)
#pragma unroll
            for (int r = 0; r < 4; ++r) {
                size_t row = bm + wr * 64 + mi * 16 + 4 * g + r;
                size_t col = bn + wc * 32 + ni * 16 + cl;
                if (OUT_BF16)
                    ((u16*)Cp)[row * ldC + col] = f2bf(acc[mi][ni][r]);
                else
                    ((float*)Cp)[row * ldC + col] = acc[mi][ni][r];
            }
}

// ---------------- MFMA flash attention with 2-deep ping-pong prefetch.
// Steady chunks are mask-free; prefetch is unconditional (buffers padded by 4 tiles).
__global__ __launch_bounds__(256) void attn_mfma(const u16* __restrict__ qb,
                                                 const u16* __restrict__ kpack,
                                                 const u16* __restrict__ vpack,
                                                 const float* __restrict__ raw_map,
                                                 const float* __restrict__ wscale,
                                                 const float* __restrict__ subln,
                                                 u16* __restrict__ outb) {
    __shared__ __align__(16) char smem[21504];   // union: plds (15360 B) / red (21504 B)
    const int tid = threadIdx.x;
    const int lane = tid & 63;
    const int wv = tid >> 6;
    const int col = lane & 15;
    const int g = lane >> 4;
    const int qbase = (127 - (int)blockIdx.x) * 16;   // heaviest blocks first (LPT)
    const int h = blockIdx.y;
    const int kvh = h >> 1;
    const int nchunks = (qbase + 16 + 31) >> 5;
    const int nfull = nchunks - 1;                    // mask-free chunks

    u16 (*plds)[16][40] = ((u16(*)[16][40])smem) + wv * 3;  // wave-private P tiles
    float (*red)[84] = (float(*)[84])smem;                   // epilogue reduce buffer

    bf16x8 qfrag[3];
#pragma unroll
    for (int m = 0; m < 3; ++m)
        qfrag[m] = *(const bf16x8*)(qb + (size_t)(qbase + col) * E_DIM + m * 512 + h * 32 + 8 * g);

    f32x4 oacc[3][6];
#pragma unroll
    for (int m = 0; m < 3; ++m)
#pragma unroll
        for (int ft = 0; ft < 6; ++ft) oacc[m][ft] = (f32x4){0.f, 0.f, 0.f, 0.f};
    float lsum[3] = {0.f, 0.f, 0.f};

    const int laneoff = col * 32 + 8 * g;
    const u16* kt = kpack + (size_t)(kvh * 64 + wv) * 3072;
    const u16* vt = vpack + (size_t)(kvh * 64 + wv) * 3072;

#define LOADKV(KF, VF)                                                     \
    do {                                                                   \
        _Pragma("unroll") for (int u = 0; u < 6; ++u)                      \
            KF[u] = *(const bf16x8*)(kt + laneoff + u * 512);              \
        _Pragma("unroll") for (int u = 0; u < 6; ++u)                      \
            VF[u] = *(const bf16x8*)(vt + laneoff + u * 512);              \
        kt += 4 * 3072;                                                    \
        vt += 4 * 3072;                                                    \
    } while (0)

#define CHUNK_COMPUTE(KF, VF)                                                          \
    do {                                                                               \
        _Pragma("unroll") for (int m = 0; m < 3; ++m) {                                \
            _Pragma("unroll") for (int st = 0; st < 2; ++st) {                         \
                f32x4 sv = __builtin_amdgcn_mfma_f32_16x16x32_bf16(                    \
                    KF[m * 2 + st], qfrag[m], (f32x4){0.f, 0.f, 0.f, 0.f}, 0, 0, 0);   \
                float p0 = __builtin_amdgcn_exp2f(sv[0]);                              \
                float p1 = __builtin_amdgcn_exp2f(sv[1]);                              \
                float p2 = __builtin_amdgcn_exp2f(sv[2]);                              \
                float p3 = __builtin_amdgcn_exp2f(sv[3]);                              \
                lsum[m] += (p0 + p1) + (p2 + p3);                                      \
                __hip_bfloat162 b01 = __float22bfloat162_rn(make_float2(p0, p1));      \
                __hip_bfloat162 b23 = __float22bfloat162_rn(make_float2(p2, p3));      \
                uint2 w;                                                               \
                w.x = *(u32*)&b01;                                                     \
                w.y = *(u32*)&b23;                                                     \
                *(uint2*)&plds[m][col][st * 16 + 4 * g] = w;                           \
            }                                                                          \
        }                                                                              \
        bf16x8 pf[3];                                                                  \
        _Pragma("unroll") for (int m = 0; m < 3; ++m)                                  \
            pf[m] = *(const bf16x8*)&plds[m][col][8 * g];                              \
        _Pragma("unroll") for (int ft = 0; ft < 6; ++ft)                               \
            _Pragma("unroll") for (int m = 0; m < 3; ++m)                              \
                oacc[m][ft] = __builtin_amdgcn_mfma_f32_16x16x32_bf16(                 \
                    pf[m], VF[ft], oacc[m][ft], 0, 0, 0);                              \
    } while (0)

    // ---- steady state: mask-free, 2-deep ping-pong prefetch
    const int n = (wv < nfull) ? ((nfull - wv + 3) >> 2) : 0;
    if (n > 0) {
        bf16x8 kfA[6], vfA[6], kfB[6], vfB[6];
        LOADKV(kfA, vfA);
        int it = 0;
        for (; it + 2 <= n; it += 2) {
            LOADKV(kfB, vfB);
            CHUNK_COMPUTE(kfA, vfA);
            LOADKV(kfA, vfA);           // may prefetch past end: padded, never consumed
            CHUNK_COMPUTE(kfB, vfB);
        }
        if (it < n) CHUNK_COMPUTE(kfA, vfA);
    }

    // ---- boundary chunk (the only one needing the causal mask)
    if ((nfull & 3) == wv) {
        const int s0 = nfull << 5;
        const u16* ktm = kpack + (size_t)(kvh * 64 + nfull) * 3072 + laneoff;
        const u16* vtm = vpack + (size_t)(kvh * 64 + nfull) * 3072 + laneoff;
        bf16x8 kf[6], vf[6];
#pragma unroll
        for (int u = 0; u < 6; ++u) kf[u] = *(const bf16x8*)(ktm + u * 512);
#pragma unroll
        for (int u = 0; u < 6; ++u) vf[u] = *(const bf16x8*)(vtm + u * 512);

#pragma unroll
        for (int m = 0; m < 3; ++m) {
#pragma unroll
            for (int st = 0; st < 2; ++st) {
                f32x4 sv = __builtin_amdgcn_mfma_f32_16x16x32_bf16(
                    kf[m * 2 + st], qfrag[m], (f32x4){0.f, 0.f, 0.f, 0.f}, 0, 0, 0);
                float p[4];
#pragma unroll
                for (int r = 0; r < 4; ++r) {
                    float x = sv[r];
                    if (s0 + st * 16 + 4 * g + r > qbase + col) x = -1e30f;
                    p[r] = __builtin_amdgcn_exp2f(x);
                    lsum[m] += p[r];
                }
                __hip_bfloat162 b01 = __float22bfloat162_rn(make_float2(p[0], p[1]));
                __hip_bfloat162 b23 = __float22bfloat162_rn(make_float2(p[2], p[3]));
                uint2 w;
                w.x = *(u32*)&b01;
                w.y = *(u32*)&b23;
                *(uint2*)&plds[m][col][st * 16 + 4 * g] = w;
            }
        }
        bf16x8 pf[3];
#pragma unroll
        for (int m = 0; m < 3; ++m)
            pf[m] = *(const bf16x8*)&plds[m][col][8 * g];
#pragma unroll
        for (int ft = 0; ft < 6; ++ft)
#pragma unroll
            for (int m = 0; m < 3; ++m)
                oacc[m][ft] = __builtin_amdgcn_mfma_f32_16x16x32_bf16(pf[m], vf[ft], oacc[m][ft], 0, 0, 0);
    }

    // ---- cross-wave reduction (additive partials) into wave 0
    __syncthreads();   // plds dead everywhere; red takes over the union
#pragma unroll
    for (int src = 1; src < 4; ++src) {
        if (wv == src) {
            float4* rp = (float4*)red[lane];
#pragma unroll
            for (int m = 0; m < 3; ++m)
#pragma unroll
                for (int ft = 0; ft < 6; ++ft)
                    rp[m * 6 + ft] = make_float4(oacc[m][ft][0], oacc[m][ft][1],
                                                 oacc[m][ft][2], oacc[m][ft][3]);
            red[lane][72] = lsum[0];
            red[lane][73] = lsum[1];
            red[lane][74] = lsum[2];
        }
        __syncthreads();
        if (wv == 0) {
            const float4* rp = (const float4*)red[lane];
#pragma unroll
            for (int m = 0; m < 3; ++m)
#pragma unroll
                for (int ft = 0; ft < 6; ++ft) {
                    float4 a = rp[m * 6 + ft];
                    oacc[m][ft][0] += a.x; oacc[m][ft][1] += a.y;
                    oacc[m][ft][2] += a.z; oacc[m][ft][3] += a.w;
                }
            lsum[0] += red[lane][72];
            lsum[1] += red[lane][73];
            lsum[2] += red[lane][74];
        }
        __syncthreads();
    }
    if (wv != 0) return;

    // ---- epilogue (wave 0): finish row sums, combine ensembles, RMS + subln
#pragma unroll
    for (int m = 0; m < 3; ++m) {
        lsum[m] += __shfl_xor(lsum[m], 16, 64);
        lsum[m] += __shfl_xor(lsum[m], 32, 64);
    }
    float wsc = wscale[0];
    float mw[3];
#pragma unroll
    for (int m = 0; m < 3; ++m) mw[m] = tanhf(raw_map[m]) * wsc;

    float fac[3][4];
#pragma unroll
    for (int m = 0; m < 3; ++m)
#pragma unroll
        for (int r = 0; r < 4; ++r)
            fac[m][r] = mw[m] / __shfl(lsum[m], 4 * g + r, 64);

    float av[6][4];
    float ss[4] = {0.f, 0.f, 0.f, 0.f};
#pragma unroll
    for (int ft = 0; ft < 6; ++ft)
#pragma unroll
        for (int r = 0; r < 4; ++r) {
            float v = fac[0][r] * oacc[0][ft][r] + fac[1][r] * oacc[1][ft][r] + fac[2][r] * oacc[2][ft][r];
            av[ft][r] = v;
            ss[r] += v * v;
        }
#pragma unroll
    for (int r = 0; r < 4; ++r) {
        ss[r] += __shfl_xor(ss[r], 1, 64);
        ss[r] += __shfl_xor(ss[r], 2, 64);
        ss[r] += __shfl_xor(ss[r], 4, 64);
        ss[r] += __shfl_xor(ss[r], 8, 64);
        ss[r] = rsqrtf(ss[r] * (1.f / 96.f) + 1e-5f);
    }
#pragma unroll
    for (int ft = 0; ft < 6; ++ft) {
        float sl = subln[ft * 16 + col];
#pragma unroll
        for (int r = 0; r < 4; ++r) {
            int trow = qbase + 4 * g + r;
            outb[(size_t)trow * E_DIM + h * 96 + ft * 16 + col] = f2bf(av[ft][r] * ss[r] * sl);
        }
    }
}

extern "C" void kernel_launch(void* const* d_in, const int* in_sizes, int n_in,
                              void* d_out, int out_size, void* d_ws, size_t ws_size,
                              hipStream_t stream) {
    const float* x       = (const float*)d_in[0];
    const float* cosb    = (const float*)d_in[1];
    const float* sinb    = (const float*)d_in[2];
    const float* q_w     = (const float*)d_in[3];
    const float* k_w     = (const float*)d_in[4];
    const float* v_w     = (const float*)d_in[5];
    const float* out_w   = (const float*)d_in[6];
    const float* raw_map = (const float*)d_in[7];
    const float* wscale  = (const float*)d_in[8];
    const float* subln   = (const float*)d_in[9];
    float* out = (float*)d_out;

    char* ws = (char*)d_ws;
    u16* xb16   = (u16*)(ws);                    // 2048x1536  (6,291,456 B)  [ab16 alias later]
    u16* wqkv16 = (u16*)(ws + 6291456);          // 3072x1536  (9,437,184 B)
    u16* qb16   = (u16*)(ws + 15728640);         // 2048x1536  (6,291,456 B)
    u16* kpack  = (u16*)(ws + 22020096);         // 8x64x3x2x16x32 (3,145,728 B) + 24,576 pad
    u16* vpack  = (u16*)(ws + 25190400);         // 8x64x96x32     (3,145,728 B) + 24,576 pad
    u16* wout16 = (u16*)(ws + 28360704);         // 1536x1536  (4,718,592 B)   -> ends 33,079,296
    u16* ab16   = xb16;                          // alias: x dead after QKV gemm

    // f32 -> bf16 conversions
    cvt_bf16<<<3072, 256, 0, stream>>>(x, xb16, 786432);
    cvt_bf16<<<2304, 256, 0, stream>>>(q_w, wqkv16, 589824);
    cvt_bf16<<<1152, 256, 0, stream>>>(k_w, wqkv16 + 2359296, 294912);
    cvt_bf16<<<1152, 256, 0, stream>>>(v_w, wqkv16 + 3538944, 294912);
    cvt_bf16<<<2304, 256, 0, stream>>>(out_w, wout16, 589824);

    // fused QKV projection + RoPE + pack. Q gets hd^-0.5 * log2(e) folded.
    const float qscale = 0.17677669529663687f * 1.4426950408889634f;
    gemm_qkv_fused<<<dim3(3072 / 64, T_DIM / 128), 256, 0, stream>>>(
        xb16, wqkv16, cosb, sinb, qb16, kpack, vpack, qscale);

    // attention + combine + RMS + subln -> bf16
    attn_mfma<<<dim3(T_DIM / 16, 16), 256, 0, stream>>>(qb16, kpack, vpack, raw_map, wscale, subln, ab16);

    // output projection: [2048,1536] x [1536,1536]^T -> f32 d_out
    gemm_mfma<0><<<dim3(E_DIM / 64, T_DIM / 128), 256, 0, stream>>>(ab16, wout16, out, K_DIM, E_DIM);
}